// Round 20
// baseline (736.822 us; speedup 1.0000x reference)
//
#include <hip/hip_runtime.h>
#include <stdint.h>

// Problem constants (B=4,S=2048 -> T=8192 tokens). Inputs fp32, OUTPUT fp32.
#define T_TOK 8192
#define DDIM  2048
#define NEXP  8
#define FDIM  1024
#define CAP   25600   // 16384 assignments + 8*128 pad + 8192 shared rows
#define NT_M  200     // CAP/128 M-tiles
#define BK    64
#define GXT   16      // grid x (f/d tiles) for both stages
#define NBLK  (GXT * NT_M)   // 3200, divisible by 8
#define CPX   (NBLK / 8)     // 400 blocks per XCD chunk
#define NRG   1728           // transpose regions: 1152 (D->F) + 576 (F->D)

typedef __bf16 bf16x8 __attribute__((ext_vector_type(8)));
typedef float  f32x4  __attribute__((ext_vector_type(4)));

typedef const __attribute__((address_space(1))) uint32_t* as1_u32;
typedef __attribute__((address_space(3))) uint32_t* as3_u32;

__device__ __forceinline__ void gload16(const void* g, void* l) {
  __builtin_amdgcn_global_load_lds((as1_u32)g, (as3_u32)l, 16, 0, 0);
}
__device__ __forceinline__ float bf2f(uint16_t u) {
  union { uint32_t i; float f; } v; v.i = ((uint32_t)u) << 16; return v.f;
}
__device__ __forceinline__ uint16_t f2bf(float f) {
  union { float f; uint32_t i; } v; v.f = f;
  uint32_t i = v.i;
  i += 0x7FFFu + ((i >> 16) & 1u);   // RNE
  return (uint16_t)(i >> 16);
}
// padded prefix offsets from 8 counts (inline everywhere)
__device__ __forceinline__ void mk_offs(const int* __restrict__ counts, int* o) {
  int a = 0;
  #pragma unroll
  for (int e = 0; e < NEXP; e++) { o[e] = a; a += (counts[e] + 127) & ~127; }
  o[8] = a; o[9] = a + T_TOK;
}

#define SWZ(c) ((((c) >> 2) & 15) << 3)   // LDS r-swizzle (bits 3-6)

// ---------------------------------------------------------------------------
// K_router: RMSNorm + router, wave-per-token, router_w staged through LDS in
// 8KB chunks (kills the 128B-stride gather transaction-splitting).
// Accumulation order identical to the proven r12 version.
// ---------------------------------------------------------------------------
__global__ __launch_bounds__(256) void k_router(
    const float* __restrict__ x, const float* __restrict__ rmsw,
    const float* __restrict__ router_w, uint16_t* __restrict__ h,
    int* __restrict__ topi, float* __restrict__ topw, int* __restrict__ counts)
{
  __shared__ float rwT[8][260];   // [e][local row] ~8.1 KB
  int tid = threadIdx.x;
  int wv = tid >> 6, lane = tid & 63;
  int t = blockIdx.x * 4 + wv;
  const float* xr = x + (size_t)t * DDIM;

  float4 xv[8], wv8[8];
  #pragma unroll
  for (int j = 0; j < 8; j++) {
    xv[j]  = ((const float4*)xr)[j * 64 + lane];
    wv8[j] = ((const float4*)rmsw)[j * 64 + lane];
  }
  float ss = 0.f;
  #pragma unroll
  for (int j = 0; j < 8; j++)
    ss += xv[j].x * xv[j].x + xv[j].y * xv[j].y + xv[j].z * xv[j].z + xv[j].w * xv[j].w;
  #pragma unroll
  for (int m = 32; m >= 1; m >>= 1) ss += __shfl_xor(ss, m, 64);
  float scale = rsqrtf(ss * (1.0f / DDIM) + 1e-6f);

  float hv[8][4];
  #pragma unroll
  for (int j = 0; j < 8; j++) {
    hv[j][0] = xv[j].x * scale * wv8[j].x;
    hv[j][1] = xv[j].y * scale * wv8[j].y;
    hv[j][2] = xv[j].z * scale * wv8[j].z;
    hv[j][3] = xv[j].w * scale * wv8[j].w;
    ushort4 hw;
    hw.x = f2bf(hv[j][0]); hw.y = f2bf(hv[j][1]);
    hw.z = f2bf(hv[j][2]); hw.w = f2bf(hv[j][3]);
    ((ushort4*)(h + (size_t)t * DDIM))[j * 64 + lane] = hw;
  }

  float lp[8] = {0, 0, 0, 0, 0, 0, 0, 0};
  #pragma unroll 1
  for (int j = 0; j < 8; j++) {
    __syncthreads();   // protect previous chunk reads
    {
      // coalesced: thread tid loads row j*256+tid (32B), scatters to rwT[e][tid]
      const float* rrow = router_w + (size_t)(j * 256 + tid) * NEXP;
      float4 a = ((const float4*)rrow)[0];
      float4 b = ((const float4*)rrow)[1];
      rwT[0][tid] = a.x; rwT[1][tid] = a.y; rwT[2][tid] = a.z; rwT[3][tid] = a.w;
      rwT[4][tid] = b.x; rwT[5][tid] = b.y; rwT[6][tid] = b.z; rwT[7][tid] = b.w;
    }
    __syncthreads();
    // lane's rows: local (lane*4+c)  <->  global (j*64+lane)*4+c
    #pragma unroll
    for (int c = 0; c < 4; c++) {
      float hj = hv[j][c];
      #pragma unroll
      for (int e = 0; e < 8; e++) lp[e] += hj * rwT[e][lane * 4 + c];
    }
  }
  #pragma unroll
  for (int m = 32; m >= 1; m >>= 1) {
    #pragma unroll
    for (int e = 0; e < 8; e++) lp[e] += __shfl_xor(lp[e], m, 64);
  }
  if (lane == 0) {
    int i0 = 0;
    for (int e = 1; e < 8; e++) if (lp[e] > lp[i0]) i0 = e;   // earliest max
    int i1 = (i0 == 0) ? 1 : 0;
    for (int e = 0; e < 8; e++) if (e != i0 && lp[e] > lp[i1]) i1 = e;
    float p0 = 1.f / (1.f + expf(lp[i1] - lp[i0]));  // renormalized top-2
    topi[t * 2] = i0; topi[t * 2 + 1] = i1;
    topw[t * 2] = p0; topw[t * 2 + 1] = 1.f - p0;
    atomicAdd(&counts[i0], 1);
    atomicAdd(&counts[i1], 1);
  }
}

// ---------------------------------------------------------------------------
// K_tr: ALL weight convert-transposes (big 256x128 regions, 64KB bf16 LDS,
// 512B-contiguous reads AND writes). r18-proven body.
// ---------------------------------------------------------------------------
__global__ __launch_bounds__(256) void k_tr(
    const float* __restrict__ wg, const float* __restrict__ wu,
    const float* __restrict__ sg, const float* __restrict__ su,
    const float* __restrict__ wd, const float* __restrict__ sd,
    uint16_t* __restrict__ wgT, uint16_t* __restrict__ wuT,
    uint16_t* __restrict__ sgT, uint16_t* __restrict__ suT,
    uint16_t* __restrict__ wdT, uint16_t* __restrict__ sdT)
{
  __shared__ uint16_t lds[128 * 256];   // 64 KB
  int flat = blockIdx.x;
  int t = threadIdx.x;
  const float* src; uint16_t* dst;
  int Csrc, Rdst, r0, c0;
  if (flat < 1152) {                // D->F: [2048][1024] -> [1024][2048]
    int z = flat >> 6, rem = flat & 63;
    Csrc = FDIM; Rdst = DDIM;
    r0 = (rem >> 3) << 8;
    c0 = (rem & 7) << 7;
    if (z < 8)       { src = wg + (size_t)z * DDIM * FDIM;       dst = wgT + (size_t)z * FDIM * DDIM; }
    else if (z < 16) { src = wu + (size_t)(z - 8) * DDIM * FDIM; dst = wuT + (size_t)(z - 8) * FDIM * DDIM; }
    else if (z == 16){ src = sg; dst = sgT; }
    else             { src = su; dst = suT; }
  } else {                          // F->D: [1024][2048] -> [2048][1024]
    int f2 = flat - 1152;
    int z = f2 >> 6, rem = f2 & 63;
    Csrc = DDIM; Rdst = FDIM;
    r0 = (rem >> 4) << 8;
    c0 = (rem & 15) << 7;
    if (z < 8) { src = wd + (size_t)z * FDIM * DDIM; dst = wdT + (size_t)z * DDIM * FDIM; }
    else       { src = sd; dst = sdT; }
  }
  int sub = t >> 5;
  int cq = (t & 31) * 4;
  #pragma unroll 4
  for (int it = 0; it < 32; it++) {
    int r = it * 8 + sub;
    float4 v = *(const float4*)(src + (size_t)(r0 + r) * Csrc + c0 + cq);
    lds[(cq + 0) * 256 + (r ^ SWZ(cq + 0))] = f2bf(v.x);
    lds[(cq + 1) * 256 + (r ^ SWZ(cq + 1))] = f2bf(v.y);
    lds[(cq + 2) * 256 + (r ^ SWZ(cq + 2))] = f2bf(v.z);
    lds[(cq + 3) * 256 + (r ^ SWZ(cq + 3))] = f2bf(v.w);
  }
  __syncthreads();
  #pragma unroll 4
  for (int it = 0; it < 16; it++) {
    int chunk = it * 256 + t;
    int cl = chunk >> 5;
    int rch = (chunk & 31) * 8;
    uint4 o = *(const uint4*)(lds + cl * 256 + (rch ^ SWZ(cl)));
    *(uint4*)(dst + (size_t)(c0 + cl) * Rdst + r0 + rch) = o;
  }
}

// ---------------------------------------------------------------------------
// K3: scatter (offsets computed inline from counts).
// ---------------------------------------------------------------------------
__global__ __launch_bounds__(256) void k_scatter(
    const int* __restrict__ topi, const float* __restrict__ topw,
    const int* __restrict__ counts, int* __restrict__ cursor,
    int* __restrict__ tokslot, float* __restrict__ wtrow)
{
  int offs[10];
  mk_offs(counts, offs);
  int idx = blockIdx.x * 256 + threadIdx.x;   // 0..24575
  if (idx < T_TOK * 2) {
    int t = idx >> 1, k = idx & 1;
    int e = topi[idx];
    int slot = atomicAdd(&cursor[e], 1);
    int row = offs[e] + slot;
    tokslot[row] = t * 4 + k;
    wtrow[row] = topw[idx];
  } else {
    int t = idx - T_TOK * 2;
    int row = offs[8] + t;
    tokslot[row] = t * 4 + 2;
    wtrow[row] = 1.0f;
  }
}

// ---------------------------------------------------------------------------
// GEMM core (proven): 128x128 tile, 4 waves, 64KB dbuf LDS, one
// __syncthreads per K-tile, T2 swizzle, T5 setprio, T1 XCD remap.
// ---------------------------------------------------------------------------
#define BUFA(c) (ldsu + (size_t)(c) * 16384)
#define BUFB(c) (ldsu + 8192 + (size_t)(c) * 16384)

#define XCD_REMAP()                                                            \
  int flat_ = blockIdx.y * GXT + blockIdx.x;                                   \
  int nf_ = (flat_ & 7) * CPX + (flat_ >> 3);                                  \
  int bx = nf_ & (GXT - 1);                                                    \
  int by = nf_ / GXT;

#define STAGE8(T, C) do {                                                     \
  _Pragma("unroll") for (int i_ = 0; i_ < 4; i_++) {                          \
    int G_ = w * 256 + i_ * 64 + lane;                                        \
    gload16(aSrc[i_] + (size_t)(T) * BK, BUFA(C) + G_ * 8);                   \
    gload16(bSrc[i_] + (size_t)(T) * BK, BUFB(C) + G_ * 8);                   \
  } } while (0)

#define COMPUTE_TILE(curA, curB) do {                                         \
  _Pragma("unroll") for (int ks_ = 0; ks_ < 2; ks_++) {                       \
    int ce_ = ks_ * 32 + ((lane >> 4) << 3);                                  \
    bf16x8 av_[4], bv_[4];                                                    \
    _Pragma("unroll") for (int m_ = 0; m_ < 4; m_++) {                        \
      int rr_ = wr * 64 + m_ * 16 + (lane & 15);                              \
      av_[m_] = *(const bf16x8*)((curA) + rr_ * 64 + (ce_ ^ ((rr_ & 7) << 3))); \
    }                                                                         \
    _Pragma("unroll") for (int n_ = 0; n_ < 4; n_++) {                        \
      int rr_ = wc * 64 + n_ * 16 + (lane & 15);                              \
      bv_[n_] = *(const bf16x8*)((curB) + rr_ * 64 + (ce_ ^ ((rr_ & 7) << 3))); \
    }                                                                         \
    __builtin_amdgcn_s_setprio(1);                                            \
    _Pragma("unroll") for (int m_ = 0; m_ < 4; m_++)                          \
    _Pragma("unroll") for (int n_ = 0; n_ < 4; n_++)                          \
      acc[m_][n_] = __builtin_amdgcn_mfma_f32_16x16x32_bf16(av_[m_], bv_[n_], acc[m_][n_], 0, 0, 0); \
    __builtin_amdgcn_s_setprio(0);                                            \
  } } while (0)

// ---------------------------------------------------------------------------
// K5: stage-1 grouped GEMM. Interleaved gate/up B-layout (16-row blocks).
// ---------------------------------------------------------------------------
__global__ __launch_bounds__(256, 2) void k_stage1(
    const uint16_t* __restrict__ h, const uint16_t* __restrict__ wgT,
    const uint16_t* __restrict__ wuT, const uint16_t* __restrict__ sgT,
    const uint16_t* __restrict__ suT, const int* __restrict__ counts,
    const int* __restrict__ tokslot, uint16_t* __restrict__ A_int)
{
  __shared__ __align__(16) uint16_t ldsu[32768];   // 64 KB

  int offs[10];
  mk_offs(counts, offs);
  XCD_REMAP();
  int row0 = by * 128;
  int end = offs[9];
  if (row0 >= end) return;
  int e = 0;
  #pragma unroll 1
  for (; e < 9; e++) if (row0 >= offs[e] && row0 < offs[e + 1]) break;
  const uint16_t* bg = (e < NEXP) ? wgT + (size_t)e * FDIM * DDIM : sgT;
  const uint16_t* bu = (e < NEXP) ? wuT + (size_t)e * FDIM * DDIM : suT;
  int f0 = bx * 64;

  int tid = threadIdx.x, lane = tid & 63, w = tid >> 6;
  int wr = w & 1, wc = w >> 1;

  const uint16_t* aSrc[4];
  const uint16_t* bSrc[4];
  #pragma unroll
  for (int i = 0; i < 4; i++) {
    int G = w * 256 + i * 64 + lane;
    int r = G >> 3, sl = G & 7;
    int gl = sl ^ (r & 7);
    int ts = tokslot[row0 + r];
    int tok = ts < 0 ? 0 : (ts >> 2);
    aSrc[i] = h + (size_t)tok * DDIM + gl * 8;
    int b = r >> 4;
    int fc = f0 + ((b >> 1) << 4) + (r & 15);
    const uint16_t* wbase = (b & 1) ? bu : bg;
    bSrc[i] = wbase + (size_t)fc * DDIM + gl * 8;
  }

  f32x4 acc[4][4] = {};
  const int NT = DDIM / BK;   // 32

  STAGE8(0, 0);
  __syncthreads();

  #pragma unroll 1
  for (int t = 0; t < NT; ++t) {
    int cur = t & 1;
    if (t + 1 < NT) STAGE8(t + 1, cur ^ 1);
    const uint16_t* curA = BUFA(cur);
    const uint16_t* curB = BUFB(cur);
    COMPUTE_TILE(curA, curB);
    __syncthreads();   // drains vmcnt (t+1 staged) + barrier
  }

  // epilogue: pairs are wave-local (acc[m][2p]=gate, acc[m][2p+1]=up)
  #pragma unroll
  for (int m = 0; m < 4; m++) {
    #pragma unroll
    for (int p = 0; p < 2; p++) {
      #pragma unroll
      for (int r = 0; r < 4; r++) {
        int row = row0 + wr * 64 + m * 16 + ((lane >> 4) << 2) + r;
        int col = f0 + wc * 32 + p * 16 + (lane & 15);
        float g = acc[m][2 * p][r];
        float u = acc[m][2 * p + 1][r];
        float a = (g / (1.f + expf(-g))) * u;
        A_int[(size_t)row * FDIM + col] = f2bf(a);
      }
    }
  }
}

// ---------------------------------------------------------------------------
// K6: stage-2 grouped GEMM: EO = A_int @ W_down. Same core.
// ---------------------------------------------------------------------------
__global__ __launch_bounds__(256, 2) void k_stage2(
    const uint16_t* __restrict__ A_int, const uint16_t* __restrict__ wdT,
    const uint16_t* __restrict__ sdT, const int* __restrict__ counts,
    const int* __restrict__ tokslot, const float* __restrict__ wtrow,
    uint16_t* __restrict__ eo, float* __restrict__ out)
{
  __shared__ __align__(16) uint16_t ldsu[32768];   // 64 KB

  int offs[10];
  mk_offs(counts, offs);
  XCD_REMAP();
  int row0 = by * 128;
  int end = offs[9];
  if (row0 >= end) return;
  int e = 0;
  #pragma unroll 1
  for (; e < 9; e++) if (row0 >= offs[e] && row0 < offs[e + 1]) break;
  const uint16_t* bw = (e < NEXP) ? wdT + (size_t)e * DDIM * FDIM : sdT;
  int d0 = bx * 128;

  int tid = threadIdx.x, lane = tid & 63, w = tid >> 6;
  int wr = w & 1, wc = w >> 1;

  const uint16_t* aSrc[4];
  const uint16_t* bSrc[4];
  #pragma unroll
  for (int i = 0; i < 4; i++) {
    int G = w * 256 + i * 64 + lane;
    int r = G >> 3, sl = G & 7;
    int gl = sl ^ (r & 7);
    aSrc[i] = A_int + (size_t)(row0 + r) * FDIM + gl * 8;
    bSrc[i] = bw + (size_t)(d0 + r) * FDIM + gl * 8;
  }

  f32x4 acc[4][4] = {};
  const int NT = FDIM / BK;   // 16

  STAGE8(0, 0);
  __syncthreads();

  #pragma unroll 1
  for (int t = 0; t < NT; ++t) {
    int cur = t & 1;
    if (t + 1 < NT) STAGE8(t + 1, cur ^ 1);
    const uint16_t* curA = BUFA(cur);
    const uint16_t* curB = BUFB(cur);
    COMPUTE_TILE(curA, curB);
    __syncthreads();
  }

  #pragma unroll
  for (int m = 0; m < 4; m++) {
    #pragma unroll
    for (int r = 0; r < 4; r++) {
      int grow = row0 + wr * 64 + m * 16 + ((lane >> 4) << 2) + r;
      int ts = tokslot[grow];
      if (ts < 0) continue;                  // padded row
      int tok = ts >> 2, slot = ts & 3;
      if (slot == 2) {                       // shared expert -> fp32 out
        size_t obase = (size_t)tok * DDIM;
        #pragma unroll
        for (int n = 0; n < 4; n++) {
          int col = d0 + wc * 64 + n * 16 + (lane & 15);
          out[obase + col] = acc[m][n][r];
        }
      } else {                               // routed -> bf16 weighted slot
        float wt = wtrow[grow];
        size_t obase = ((size_t)tok * 2 + slot) * DDIM;
        #pragma unroll
        for (int n = 0; n < 4; n++) {
          int col = d0 + wc * 64 + n * 16 + (lane & 15);
          eo[obase + col] = f2bf(acc[m][n][r] * wt);
        }
      }
    }
  }
}

// ---------------------------------------------------------------------------
// K7: out = out_shared(fp32) + eo[slot0](bf16) + eo[slot1](bf16)
// ---------------------------------------------------------------------------
__global__ __launch_bounds__(256) void k_final(
    const uint16_t* __restrict__ eo, float* __restrict__ out)
{
  int tok = blockIdx.x;
  int col = threadIdx.x * 8;
  const uint16_t* e0 = eo + ((size_t)tok * 2) * DDIM + col;
  const uint16_t* e1 = eo + ((size_t)tok * 2 + 1) * DDIM + col;
  float* op = out + (size_t)tok * DDIM + col;
  ushort4 a0 = *(const ushort4*)(e0);
  ushort4 a1 = *(const ushort4*)(e0 + 4);
  ushort4 b0 = *(const ushort4*)(e1);
  ushort4 b1 = *(const ushort4*)(e1 + 4);
  float4 s0 = *(const float4*)(op);
  float4 s1 = *(const float4*)(op + 4);
  float4 o0, o1;
  o0.x = s0.x + bf2f(a0.x) + bf2f(b0.x);
  o0.y = s0.y + bf2f(a0.y) + bf2f(b0.y);
  o0.z = s0.z + bf2f(a0.z) + bf2f(b0.z);
  o0.w = s0.w + bf2f(a0.w) + bf2f(b0.w);
  o1.x = s1.x + bf2f(a1.x) + bf2f(b1.x);
  o1.y = s1.y + bf2f(a1.y) + bf2f(b1.y);
  o1.z = s1.z + bf2f(a1.z) + bf2f(b1.z);
  o1.w = s1.w + bf2f(a1.w) + bf2f(b1.w);
  *(float4*)(op) = o0;
  *(float4*)(op + 4) = o1;
}

// ---------------------------------------------------------------------------
extern "C" void kernel_launch(void* const* d_in, const int* in_sizes, int n_in,
                              void* d_out, int out_size, void* d_ws, size_t ws_size,
                              hipStream_t stream) {
  (void)in_sizes; (void)n_in; (void)out_size;
  const float* x    = (const float*)d_in[0];
  const float* rmsw = (const float*)d_in[1];
  const float* rtw  = (const float*)d_in[2];
  const float* wg   = (const float*)d_in[3];
  const float* wu   = (const float*)d_in[4];
  const float* wd   = (const float*)d_in[5];
  const float* sg   = (const float*)d_in[6];
  const float* su   = (const float*)d_in[7];
  const float* sd   = (const float*)d_in[8];
  float* out = (float*)d_out;

  // ---- workspace layout (~200 MB; known-good budget 224.73 MB) ----
  char* base = (char*)d_ws;
  size_t off_b = 0;
  auto place = [&](size_t bytes) { size_t r = off_b; off_b += (bytes + 255) & ~(size_t)255; return r; };
  size_t o_topi    = place((size_t)T_TOK * 2 * 4);
  size_t o_topw    = place((size_t)T_TOK * 2 * 4);
  size_t o_counts  = place(64);
  size_t o_cursor  = place(64);        // adjacent to counts: one 512B memset
  size_t o_tokslot = place((size_t)CAP * 4);
  size_t o_wtrow   = place((size_t)CAP * 4);
  size_t o_h   = place((size_t)T_TOK * DDIM * 2);          // 33.55 MB
  size_t o_wgT = place((size_t)NEXP * FDIM * DDIM * 2);    // 33.55 MB
  size_t o_wuT = place((size_t)NEXP * FDIM * DDIM * 2);    // 33.55 MB
  size_t o_sgT = place((size_t)FDIM * DDIM * 2);           // 4.19 MB
  size_t o_suT = place((size_t)FDIM * DDIM * 2);           // 4.19 MB
  size_t o_wdT = place((size_t)NEXP * DDIM * FDIM * 2);    // 33.55 MB
  size_t o_sdT = place((size_t)DDIM * FDIM * 2);           // 4.19 MB
  size_t o_Ai  = place((size_t)CAP * FDIM * 2);            // 52.43 MB
  // eo (bf16 [T][2][D] = 67.11 MB) overlays h+wgT (both dead after stage1)
  size_t o_eo  = o_h;
  size_t NEED = off_b;
  if (ws_size < NEED) return;

  int*      topi    = (int*)(base + o_topi);
  float*    topw    = (float*)(base + o_topw);
  int*      counts  = (int*)(base + o_counts);
  int*      cursor  = (int*)(base + o_cursor);
  int*      tokslot = (int*)(base + o_tokslot);
  float*    wtrow   = (float*)(base + o_wtrow);
  uint16_t* h       = (uint16_t*)(base + o_h);
  uint16_t* wgT     = (uint16_t*)(base + o_wgT);
  uint16_t* wuT     = (uint16_t*)(base + o_wuT);
  uint16_t* sgT     = (uint16_t*)(base + o_sgT);
  uint16_t* suT     = (uint16_t*)(base + o_suT);
  uint16_t* wdT     = (uint16_t*)(base + o_wdT);
  uint16_t* sdT     = (uint16_t*)(base + o_sdT);
  uint16_t* Ai      = (uint16_t*)(base + o_Ai);
  uint16_t* eo      = (uint16_t*)(base + o_eo);

  hipMemsetAsync(counts, 0, 512, stream);                  // counts + cursor
  hipMemsetAsync(tokslot, 0xFF, (size_t)CAP * 4, stream);  // -1 = padded row

  k_router<<<T_TOK / 4, 256, 0, stream>>>(x, rmsw, rtw, h, topi, topw, counts);
  k_tr<<<NRG, 256, 0, stream>>>(wg, wu, sg, su, wd, sd,
                                wgT, wuT, sgT, suT, wdT, sdT);
  k_scatter<<<(T_TOK * 3) / 256, 256, 0, stream>>>(topi, topw, counts, cursor, tokslot, wtrow);

  // grids are GXT x NT_M; XCD-chunked remap happens inside the kernels
  k_stage1<<<dim3(GXT, NT_M), 256, 0, stream>>>(h, wgT, wuT, sgT, suT, counts, tokslot, Ai);
  // stage2 overwrites h/wgT (dead) as eo
  k_stage2<<<dim3(GXT, NT_M), 256, 0, stream>>>(Ai, wdT, sdT, counts, tokslot, wtrow, eo, out);
  k_final<<<T_TOK, 256, 0, stream>>>(eo, out);
}

// Round 21
// 717.911 us; speedup vs baseline: 1.0263x; 1.0263x over previous
//
#include <hip/hip_runtime.h>
#include <stdint.h>

// Problem constants (B=4,S=2048 -> T=8192 tokens). Inputs fp32, OUTPUT fp32.
#define T_TOK 8192
#define DDIM  2048
#define NEXP  8
#define FDIM  1024
#define CAP   25600   // 16384 assignments + 8*128 pad + 8192 shared rows
#define NT_M  200     // CAP/128 M-tiles
#define BK    64
#define GXT   16      // grid x (f/d tiles) for both stages
#define NBLK  (GXT * NT_M)   // 3200, divisible by 8
#define CPX   (NBLK / 8)     // 400 blocks per XCD chunk
#define NRG   1728           // transpose regions: 1152 (D->F) + 576 (F->D)

typedef __bf16 bf16x8 __attribute__((ext_vector_type(8)));
typedef float  f32x4  __attribute__((ext_vector_type(4)));

typedef const __attribute__((address_space(1))) uint32_t* as1_u32;
typedef __attribute__((address_space(3))) uint32_t* as3_u32;

__device__ __forceinline__ void gload16(const void* g, void* l) {
  __builtin_amdgcn_global_load_lds((as1_u32)g, (as3_u32)l, 16, 0, 0);
}
__device__ __forceinline__ float bf2f(uint16_t u) {
  union { uint32_t i; float f; } v; v.i = ((uint32_t)u) << 16; return v.f;
}
__device__ __forceinline__ uint16_t f2bf(float f) {
  union { float f; uint32_t i; } v; v.f = f;
  uint32_t i = v.i;
  i += 0x7FFFu + ((i >> 16) & 1u);   // RNE
  return (uint16_t)(i >> 16);
}
// padded prefix offsets from 8 counts (inline everywhere)
__device__ __forceinline__ void mk_offs(const int* __restrict__ counts, int* o) {
  int a = 0;
  #pragma unroll
  for (int e = 0; e < NEXP; e++) { o[e] = a; a += (counts[e] + 127) & ~127; }
  o[8] = a; o[9] = a + T_TOK;
}

// ---------------------------------------------------------------------------
// K_prep: blocks 0..NRG-1 = BIG-REGION convert-transposes (256 src-rows x
// 128 src-cols per block, 64KB bf16 LDS): 512B-contiguous reads AND writes.
// Blocks NRG.. = RMSNorm+router (wave-per-token). Merged launch: the
// latency-bound router waves and BW-bound transpose waves fill each other's
// bubbles (measured best config, r18 = 717.7us).
// ---------------------------------------------------------------------------
#define SWZ(c) ((((c) >> 2) & 15) << 3)   // LDS r-swizzle (bits 3-6)

__global__ __launch_bounds__(256) void k_prep(
    const float* __restrict__ wg, const float* __restrict__ wu,
    const float* __restrict__ sg, const float* __restrict__ su,
    const float* __restrict__ wd, const float* __restrict__ sd,
    const float* __restrict__ x, const float* __restrict__ rmsw,
    const float* __restrict__ router_w,
    uint16_t* __restrict__ wgT, uint16_t* __restrict__ wuT,
    uint16_t* __restrict__ sgT, uint16_t* __restrict__ suT,
    uint16_t* __restrict__ wdT, uint16_t* __restrict__ sdT,
    uint16_t* __restrict__ h, int* __restrict__ topi,
    float* __restrict__ topw, int* __restrict__ counts)
{
  __shared__ uint16_t lds[128 * 256];   // 64 KB: [c_local][r_local] (swizzled)
  int flat = blockIdx.x;
  int t = threadIdx.x;
  if (flat < NRG) {
    const float* src; uint16_t* dst;
    int Csrc, Rdst, r0, c0;
    if (flat < 1152) {                // D->F: src [2048][1024] -> dst [1024][2048]
      int z = flat >> 6, rem = flat & 63;
      Csrc = FDIM; Rdst = DDIM;
      r0 = (rem >> 3) << 8;           // 8 region-rows of 256
      c0 = (rem & 7) << 7;            // 8 region-cols of 128
      if (z < 8)       { src = wg + (size_t)z * DDIM * FDIM;       dst = wgT + (size_t)z * FDIM * DDIM; }
      else if (z < 16) { src = wu + (size_t)(z - 8) * DDIM * FDIM; dst = wuT + (size_t)(z - 8) * FDIM * DDIM; }
      else if (z == 16){ src = sg; dst = sgT; }
      else             { src = su; dst = suT; }
    } else {                          // F->D: src [1024][2048] -> dst [2048][1024]
      int f2 = flat - 1152;
      int z = f2 >> 6, rem = f2 & 63;
      Csrc = DDIM; Rdst = FDIM;
      r0 = (rem >> 4) << 8;           // 4 region-rows of 256
      c0 = (rem & 15) << 7;           // 16 region-cols of 128
      if (z < 8) { src = wd + (size_t)z * FDIM * DDIM; dst = wdT + (size_t)z * DDIM * FDIM; }
      else       { src = sd; dst = sdT; }
    }
    // phase 1: read 256x128 fp32 (512B runs), convert, LDS-transpose store
    int sub = t >> 5;                 // 0..7: row within iteration group
    int cq = (t & 31) * 4;            // col quad base 0..124
    #pragma unroll 4
    for (int it = 0; it < 32; it++) {
      int r = it * 8 + sub;
      float4 v = *(const float4*)(src + (size_t)(r0 + r) * Csrc + c0 + cq);
      lds[(cq + 0) * 256 + (r ^ SWZ(cq + 0))] = f2bf(v.x);
      lds[(cq + 1) * 256 + (r ^ SWZ(cq + 1))] = f2bf(v.y);
      lds[(cq + 2) * 256 + (r ^ SWZ(cq + 2))] = f2bf(v.z);
      lds[(cq + 3) * 256 + (r ^ SWZ(cq + 3))] = f2bf(v.w);
    }
    __syncthreads();
    // phase 2: write dst rows (c0..c0+127) x 256 cols (512B runs)
    #pragma unroll 4
    for (int it = 0; it < 16; it++) {
      int chunk = it * 256 + t;       // 0..4095
      int cl = chunk >> 5;            // dst row 0..127
      int rch = (chunk & 31) * 8;     // 8-elem col chunk
      uint4 o = *(const uint4*)(lds + cl * 256 + (rch ^ SWZ(cl)));
      *(uint4*)(dst + (size_t)(c0 + cl) * Rdst + r0 + rch) = o;
    }
  } else {
    // ---- RMSNorm + router, wave-per-token ----
    int wv = t >> 6, lane = t & 63;
    int tok = (flat - NRG) * 4 + wv;
    const float* xr = x + (size_t)tok * DDIM;

    float4 xv[8], wv8[8];
    #pragma unroll
    for (int j = 0; j < 8; j++) {
      xv[j]  = ((const float4*)xr)[j * 64 + lane];
      wv8[j] = ((const float4*)rmsw)[j * 64 + lane];
    }
    float ss = 0.f;
    #pragma unroll
    for (int j = 0; j < 8; j++)
      ss += xv[j].x * xv[j].x + xv[j].y * xv[j].y + xv[j].z * xv[j].z + xv[j].w * xv[j].w;
    #pragma unroll
    for (int m = 32; m >= 1; m >>= 1) ss += __shfl_xor(ss, m, 64);
    float scale = rsqrtf(ss * (1.0f / DDIM) + 1e-6f);

    float hv[8][4];
    #pragma unroll
    for (int j = 0; j < 8; j++) {
      hv[j][0] = xv[j].x * scale * wv8[j].x;
      hv[j][1] = xv[j].y * scale * wv8[j].y;
      hv[j][2] = xv[j].z * scale * wv8[j].z;
      hv[j][3] = xv[j].w * scale * wv8[j].w;
      ushort4 hw;
      hw.x = f2bf(hv[j][0]); hw.y = f2bf(hv[j][1]);
      hw.z = f2bf(hv[j][2]); hw.w = f2bf(hv[j][3]);
      ((ushort4*)(h + (size_t)tok * DDIM))[j * 64 + lane] = hw;
    }

    float lp[8] = {0, 0, 0, 0, 0, 0, 0, 0};
    #pragma unroll
    for (int j = 0; j < 8; j++) {
      #pragma unroll
      for (int c = 0; c < 4; c++) {
        int d = (j * 64 + lane) * 4 + c;
        const float* rw = router_w + (size_t)d * NEXP;
        float4 a = ((const float4*)rw)[0];
        float4 b = ((const float4*)rw)[1];
        float hj = hv[j][c];
        lp[0] += hj * a.x; lp[1] += hj * a.y; lp[2] += hj * a.z; lp[3] += hj * a.w;
        lp[4] += hj * b.x; lp[5] += hj * b.y; lp[6] += hj * b.z; lp[7] += hj * b.w;
      }
    }
    #pragma unroll
    for (int m = 32; m >= 1; m >>= 1) {
      #pragma unroll
      for (int e = 0; e < 8; e++) lp[e] += __shfl_xor(lp[e], m, 64);
    }
    if (lane == 0) {
      int i0 = 0;
      for (int e = 1; e < 8; e++) if (lp[e] > lp[i0]) i0 = e;   // earliest max
      int i1 = (i0 == 0) ? 1 : 0;
      for (int e = 0; e < 8; e++) if (e != i0 && lp[e] > lp[i1]) i1 = e;
      float p0 = 1.f / (1.f + expf(lp[i1] - lp[i0]));  // renormalized top-2
      topi[tok * 2] = i0; topi[tok * 2 + 1] = i1;
      topw[tok * 2] = p0; topw[tok * 2 + 1] = 1.f - p0;
      atomicAdd(&counts[i0], 1);
      atomicAdd(&counts[i1], 1);
    }
  }
}

// ---------------------------------------------------------------------------
// K3: scatter (offsets computed inline from counts).
// ---------------------------------------------------------------------------
__global__ __launch_bounds__(256) void k_scatter(
    const int* __restrict__ topi, const float* __restrict__ topw,
    const int* __restrict__ counts, int* __restrict__ cursor,
    int* __restrict__ tokslot, float* __restrict__ wtrow)
{
  int offs[10];
  mk_offs(counts, offs);
  int idx = blockIdx.x * 256 + threadIdx.x;   // 0..24575
  if (idx < T_TOK * 2) {
    int t = idx >> 1, k = idx & 1;
    int e = topi[idx];
    int slot = atomicAdd(&cursor[e], 1);
    int row = offs[e] + slot;
    tokslot[row] = t * 4 + k;
    wtrow[row] = topw[idx];
  } else {
    int t = idx - T_TOK * 2;
    int row = offs[8] + t;
    tokslot[row] = t * 4 + 2;
    wtrow[row] = 1.0f;
  }
}

// ---------------------------------------------------------------------------
// GEMM core (proven): 128x128 tile, 4 waves, 64KB dbuf LDS, one
// __syncthreads per K-tile, T2 swizzle, T5 setprio, T1 XCD remap.
// ---------------------------------------------------------------------------
#define BUFA(c) (ldsu + (size_t)(c) * 16384)
#define BUFB(c) (ldsu + 8192 + (size_t)(c) * 16384)

#define XCD_REMAP()                                                            \
  int flat_ = blockIdx.y * GXT + blockIdx.x;                                   \
  int nf_ = (flat_ & 7) * CPX + (flat_ >> 3);                                  \
  int bx = nf_ & (GXT - 1);                                                    \
  int by = nf_ / GXT;

#define STAGE8(T, C) do {                                                     \
  _Pragma("unroll") for (int i_ = 0; i_ < 4; i_++) {                          \
    int G_ = w * 256 + i_ * 64 + lane;                                        \
    gload16(aSrc[i_] + (size_t)(T) * BK, BUFA(C) + G_ * 8);                   \
    gload16(bSrc[i_] + (size_t)(T) * BK, BUFB(C) + G_ * 8);                   \
  } } while (0)

#define COMPUTE_TILE(curA, curB) do {                                         \
  _Pragma("unroll") for (int ks_ = 0; ks_ < 2; ks_++) {                       \
    int ce_ = ks_ * 32 + ((lane >> 4) << 3);                                  \
    bf16x8 av_[4], bv_[4];                                                    \
    _Pragma("unroll") for (int m_ = 0; m_ < 4; m_++) {                        \
      int rr_ = wr * 64 + m_ * 16 + (lane & 15);                              \
      av_[m_] = *(const bf16x8*)((curA) + rr_ * 64 + (ce_ ^ ((rr_ & 7) << 3))); \
    }                                                                         \
    _Pragma("unroll") for (int n_ = 0; n_ < 4; n_++) {                        \
      int rr_ = wc * 64 + n_ * 16 + (lane & 15);                              \
      bv_[n_] = *(const bf16x8*)((curB) + rr_ * 64 + (ce_ ^ ((rr_ & 7) << 3))); \
    }                                                                         \
    __builtin_amdgcn_s_setprio(1);                                            \
    _Pragma("unroll") for (int m_ = 0; m_ < 4; m_++)                          \
    _Pragma("unroll") for (int n_ = 0; n_ < 4; n_++)                          \
      acc[m_][n_] = __builtin_amdgcn_mfma_f32_16x16x32_bf16(av_[m_], bv_[n_], acc[m_][n_], 0, 0, 0); \
    __builtin_amdgcn_s_setprio(0);                                            \
  } } while (0)

// ---------------------------------------------------------------------------
// K5: stage-1 grouped GEMM. Interleaved gate/up B-layout (16-row blocks):
// r -> b=r>>4; type=b&1; fcol = f0 + (b>>1)*16 + (r&15). silu pairing is
// wave-local (acc[m][2p]=gate, acc[m][2p+1]=up).
// ---------------------------------------------------------------------------
__global__ __launch_bounds__(256, 2) void k_stage1(
    const uint16_t* __restrict__ h, const uint16_t* __restrict__ wgT,
    const uint16_t* __restrict__ wuT, const uint16_t* __restrict__ sgT,
    const uint16_t* __restrict__ suT, const int* __restrict__ counts,
    const int* __restrict__ tokslot, uint16_t* __restrict__ A_int)
{
  __shared__ __align__(16) uint16_t ldsu[32768];   // 64 KB

  int offs[10];
  mk_offs(counts, offs);
  XCD_REMAP();
  int row0 = by * 128;
  int end = offs[9];
  if (row0 >= end) return;
  int e = 0;
  #pragma unroll 1
  for (; e < 9; e++) if (row0 >= offs[e] && row0 < offs[e + 1]) break;
  const uint16_t* bg = (e < NEXP) ? wgT + (size_t)e * FDIM * DDIM : sgT;
  const uint16_t* bu = (e < NEXP) ? wuT + (size_t)e * FDIM * DDIM : suT;
  int f0 = bx * 64;

  int tid = threadIdx.x, lane = tid & 63, w = tid >> 6;
  int wr = w & 1, wc = w >> 1;

  const uint16_t* aSrc[4];
  const uint16_t* bSrc[4];
  #pragma unroll
  for (int i = 0; i < 4; i++) {
    int G = w * 256 + i * 64 + lane;
    int r = G >> 3, sl = G & 7;
    int gl = sl ^ (r & 7);
    int ts = tokslot[row0 + r];
    int tok = ts < 0 ? 0 : (ts >> 2);
    aSrc[i] = h + (size_t)tok * DDIM + gl * 8;
    int b = r >> 4;
    int fc = f0 + ((b >> 1) << 4) + (r & 15);
    const uint16_t* wbase = (b & 1) ? bu : bg;
    bSrc[i] = wbase + (size_t)fc * DDIM + gl * 8;
  }

  f32x4 acc[4][4] = {};
  const int NT = DDIM / BK;   // 32

  STAGE8(0, 0);
  __syncthreads();

  #pragma unroll 1
  for (int t = 0; t < NT; ++t) {
    int cur = t & 1;
    if (t + 1 < NT) STAGE8(t + 1, cur ^ 1);
    const uint16_t* curA = BUFA(cur);
    const uint16_t* curB = BUFB(cur);
    COMPUTE_TILE(curA, curB);
    __syncthreads();   // drains vmcnt (t+1 staged) + barrier
  }

  // epilogue: pairs are wave-local (acc[m][2p]=gate, acc[m][2p+1]=up)
  #pragma unroll
  for (int m = 0; m < 4; m++) {
    #pragma unroll
    for (int p = 0; p < 2; p++) {
      #pragma unroll
      for (int r = 0; r < 4; r++) {
        int row = row0 + wr * 64 + m * 16 + ((lane >> 4) << 2) + r;
        int col = f0 + wc * 32 + p * 16 + (lane & 15);
        float g = acc[m][2 * p][r];
        float u = acc[m][2 * p + 1][r];
        float a = (g / (1.f + expf(-g))) * u;
        A_int[(size_t)row * FDIM + col] = f2bf(a);
      }
    }
  }
}

// ---------------------------------------------------------------------------
// K6: stage-2 grouped GEMM: EO = A_int @ W_down. Same core.
// ---------------------------------------------------------------------------
__global__ __launch_bounds__(256, 2) void k_stage2(
    const uint16_t* __restrict__ A_int, const uint16_t* __restrict__ wdT,
    const uint16_t* __restrict__ sdT, const int* __restrict__ counts,
    const int* __restrict__ tokslot, const float* __restrict__ wtrow,
    uint16_t* __restrict__ eo, float* __restrict__ out)
{
  __shared__ __align__(16) uint16_t ldsu[32768];   // 64 KB

  int offs[10];
  mk_offs(counts, offs);
  XCD_REMAP();
  int row0 = by * 128;
  int end = offs[9];
  if (row0 >= end) return;
  int e = 0;
  #pragma unroll 1
  for (; e < 9; e++) if (row0 >= offs[e] && row0 < offs[e + 1]) break;
  const uint16_t* bw = (e < NEXP) ? wdT + (size_t)e * DDIM * FDIM : sdT;
  int d0 = bx * 128;

  int tid = threadIdx.x, lane = tid & 63, w = tid >> 6;
  int wr = w & 1, wc = w >> 1;

  const uint16_t* aSrc[4];
  const uint16_t* bSrc[4];
  #pragma unroll
  for (int i = 0; i < 4; i++) {
    int G = w * 256 + i * 64 + lane;
    int r = G >> 3, sl = G & 7;
    int gl = sl ^ (r & 7);
    aSrc[i] = A_int + (size_t)(row0 + r) * FDIM + gl * 8;
    bSrc[i] = bw + (size_t)(d0 + r) * FDIM + gl * 8;
  }

  f32x4 acc[4][4] = {};
  const int NT = FDIM / BK;   // 16

  STAGE8(0, 0);
  __syncthreads();

  #pragma unroll 1
  for (int t = 0; t < NT; ++t) {
    int cur = t & 1;
    if (t + 1 < NT) STAGE8(t + 1, cur ^ 1);
    const uint16_t* curA = BUFA(cur);
    const uint16_t* curB = BUFB(cur);
    COMPUTE_TILE(curA, curB);
    __syncthreads();
  }

  #pragma unroll
  for (int m = 0; m < 4; m++) {
    #pragma unroll
    for (int r = 0; r < 4; r++) {
      int grow = row0 + wr * 64 + m * 16 + ((lane >> 4) << 2) + r;
      int ts = tokslot[grow];
      if (ts < 0) continue;                  // padded row
      int tok = ts >> 2, slot = ts & 3;
      if (slot == 2) {                       // shared expert -> fp32 out
        size_t obase = (size_t)tok * DDIM;
        #pragma unroll
        for (int n = 0; n < 4; n++) {
          int col = d0 + wc * 64 + n * 16 + (lane & 15);
          out[obase + col] = acc[m][n][r];
        }
      } else {                               // routed -> bf16 weighted slot
        float wt = wtrow[grow];
        size_t obase = ((size_t)tok * 2 + slot) * DDIM;
        #pragma unroll
        for (int n = 0; n < 4; n++) {
          int col = d0 + wc * 64 + n * 16 + (lane & 15);
          eo[obase + col] = f2bf(acc[m][n][r] * wt);
        }
      }
    }
  }
}

// ---------------------------------------------------------------------------
// K7: out = out_shared(fp32) + eo[slot0](bf16) + eo[slot1](bf16)
// ---------------------------------------------------------------------------
__global__ __launch_bounds__(256) void k_final(
    const uint16_t* __restrict__ eo, float* __restrict__ out)
{
  int tok = blockIdx.x;
  int col = threadIdx.x * 8;
  const uint16_t* e0 = eo + ((size_t)tok * 2) * DDIM + col;
  const uint16_t* e1 = eo + ((size_t)tok * 2 + 1) * DDIM + col;
  float* op = out + (size_t)tok * DDIM + col;
  ushort4 a0 = *(const ushort4*)(e0);
  ushort4 a1 = *(const ushort4*)(e0 + 4);
  ushort4 b0 = *(const ushort4*)(e1);
  ushort4 b1 = *(const ushort4*)(e1 + 4);
  float4 s0 = *(const float4*)(op);
  float4 s1 = *(const float4*)(op + 4);
  float4 o0, o1;
  o0.x = s0.x + bf2f(a0.x) + bf2f(b0.x);
  o0.y = s0.y + bf2f(a0.y) + bf2f(b0.y);
  o0.z = s0.z + bf2f(a0.z) + bf2f(b0.z);
  o0.w = s0.w + bf2f(a0.w) + bf2f(b0.w);
  o1.x = s1.x + bf2f(a1.x) + bf2f(b1.x);
  o1.y = s1.y + bf2f(a1.y) + bf2f(b1.y);
  o1.z = s1.z + bf2f(a1.z) + bf2f(b1.z);
  o1.w = s1.w + bf2f(a1.w) + bf2f(b1.w);
  *(float4*)(op) = o0;
  *(float4*)(op + 4) = o1;
}

// ---------------------------------------------------------------------------
extern "C" void kernel_launch(void* const* d_in, const int* in_sizes, int n_in,
                              void* d_out, int out_size, void* d_ws, size_t ws_size,
                              hipStream_t stream) {
  (void)in_sizes; (void)n_in; (void)out_size;
  const float* x    = (const float*)d_in[0];
  const float* rmsw = (const float*)d_in[1];
  const float* rtw  = (const float*)d_in[2];
  const float* wg   = (const float*)d_in[3];
  const float* wu   = (const float*)d_in[4];
  const float* wd   = (const float*)d_in[5];
  const float* sg   = (const float*)d_in[6];
  const float* su   = (const float*)d_in[7];
  const float* sd   = (const float*)d_in[8];
  float* out = (float*)d_out;

  // ---- workspace layout (~200 MB; known-good budget 224.73 MB) ----
  char* base = (char*)d_ws;
  size_t off_b = 0;
  auto place = [&](size_t bytes) { size_t r = off_b; off_b += (bytes + 255) & ~(size_t)255; return r; };
  size_t o_topi    = place((size_t)T_TOK * 2 * 4);
  size_t o_topw    = place((size_t)T_TOK * 2 * 4);
  size_t o_counts  = place(64);
  size_t o_cursor  = place(64);        // adjacent to counts: one 512B memset
  size_t o_tokslot = place((size_t)CAP * 4);
  size_t o_wtrow   = place((size_t)CAP * 4);
  size_t o_h   = place((size_t)T_TOK * DDIM * 2);          // 33.55 MB
  size_t o_wgT = place((size_t)NEXP * FDIM * DDIM * 2);    // 33.55 MB
  size_t o_wuT = place((size_t)NEXP * FDIM * DDIM * 2);    // 33.55 MB
  size_t o_sgT = place((size_t)FDIM * DDIM * 2);           // 4.19 MB
  size_t o_suT = place((size_t)FDIM * DDIM * 2);           // 4.19 MB
  size_t o_wdT = place((size_t)NEXP * DDIM * FDIM * 2);    // 33.55 MB
  size_t o_sdT = place((size_t)DDIM * FDIM * 2);           // 4.19 MB
  size_t o_Ai  = place((size_t)CAP * FDIM * 2);            // 52.43 MB
  // eo (bf16 [T][2][D] = 67.11 MB) overlays h+wgT (both dead after stage1)
  size_t o_eo  = o_h;
  size_t NEED = off_b;
  if (ws_size < NEED) return;

  int*      topi    = (int*)(base + o_topi);
  float*    topw    = (float*)(base + o_topw);
  int*      counts  = (int*)(base + o_counts);
  int*      cursor  = (int*)(base + o_cursor);
  int*      tokslot = (int*)(base + o_tokslot);
  float*    wtrow   = (float*)(base + o_wtrow);
  uint16_t* h       = (uint16_t*)(base + o_h);
  uint16_t* wgT     = (uint16_t*)(base + o_wgT);
  uint16_t* wuT     = (uint16_t*)(base + o_wuT);
  uint16_t* sgT     = (uint16_t*)(base + o_sgT);
  uint16_t* suT     = (uint16_t*)(base + o_suT);
  uint16_t* wdT     = (uint16_t*)(base + o_wdT);
  uint16_t* sdT     = (uint16_t*)(base + o_sdT);
  uint16_t* Ai      = (uint16_t*)(base + o_Ai);
  uint16_t* eo      = (uint16_t*)(base + o_eo);

  hipMemsetAsync(counts, 0, 512, stream);                  // counts + cursor
  hipMemsetAsync(tokslot, 0xFF, (size_t)CAP * 4, stream);  // -1 = padded row

  // big-region transposes + RMSNorm/router in ONE launch
  k_prep<<<NRG + T_TOK / 4, 256, 0, stream>>>(
      wg, wu, sg, su, wd, sd, x, rmsw, rtw,
      wgT, wuT, sgT, suT, wdT, sdT, h, topi, topw, counts);

  k_scatter<<<(T_TOK * 3) / 256, 256, 0, stream>>>(topi, topw, counts, cursor, tokslot, wtrow);

  // grids are GXT x NT_M; XCD-chunked remap happens inside the kernels
  k_stage1<<<dim3(GXT, NT_M), 256, 0, stream>>>(h, wgT, wuT, sgT, suT, counts, tokslot, Ai);
  // stage2 overwrites h/wgT (dead) as eo
  k_stage2<<<dim3(GXT, NT_M), 256, 0, stream>>>(Ai, wdT, sdT, counts, tokslot, wtrow, eo, out);
  k_final<<<T_TOK, 256, 0, stream>>>(eo, out);
}

// Round 22
// 689.228 us; speedup vs baseline: 1.0691x; 1.0416x over previous
//
#include <hip/hip_runtime.h>
#include <stdint.h>

// Problem constants (B=4,S=2048 -> T=8192 tokens). Inputs fp32, OUTPUT fp32.
#define T_TOK 8192
#define DDIM  2048
#define NEXP  8
#define FDIM  1024
#define CAP   25600   // 16384 assignments + 8*128 pad + 8192 shared rows
#define NT_M  200     // CAP/128 M-tiles
#define BK    64
#define GXT   16      // grid x (f/d tiles) for both stages
#define NBLK  (GXT * NT_M)   // 3200, divisible by 8
#define CPX   (NBLK / 8)     // 400 blocks per XCD chunk
#define NRG   1728           // transpose regions: 1152 (D->F) + 576 (F->D)
#define NRT   (T_TOK / 4)    // router blocks: 2048

typedef __bf16 bf16x8 __attribute__((ext_vector_type(8)));
typedef float  f32x4  __attribute__((ext_vector_type(4)));

typedef const __attribute__((address_space(1))) uint32_t* as1_u32;
typedef __attribute__((address_space(3))) uint32_t* as3_u32;

__device__ __forceinline__ void gload16(const void* g, void* l) {
  __builtin_amdgcn_global_load_lds((as1_u32)g, (as3_u32)l, 16, 0, 0);
}
__device__ __forceinline__ float bf2f(uint16_t u) {
  union { uint32_t i; float f; } v; v.i = ((uint32_t)u) << 16; return v.f;
}
__device__ __forceinline__ uint16_t f2bf(float f) {
  union { float f; uint32_t i; } v; v.f = f;
  uint32_t i = v.i;
  i += 0x7FFFu + ((i >> 16) & 1u);   // RNE
  return (uint16_t)(i >> 16);
}
// padded prefix offsets from 8 counts (inline everywhere)
__device__ __forceinline__ void mk_offs(const int* __restrict__ counts, int* o) {
  int a = 0;
  #pragma unroll
  for (int e = 0; e < NEXP; e++) { o[e] = a; a += (counts[e] + 127) & ~127; }
  o[8] = a; o[9] = a + T_TOK;
}

// ---------------------------------------------------------------------------
// K_prep: merged transposes + router, with INTERLEAVED block families so
// every CU co-hosts BW-bound transpose waves and latency-bound router waves
// for the whole dispatch (the mechanism that made the merged launch win).
//   flat < 2*NRG (3456): even -> transpose(flat/2), odd -> router(flat/2)
//   flat >= 3456:        router(1728 + flat - 3456)
// ---------------------------------------------------------------------------
#define SWZ(c) ((((c) >> 2) & 15) << 3)   // LDS r-swizzle (bits 3-6)

__global__ __launch_bounds__(256) void k_prep(
    const float* __restrict__ wg, const float* __restrict__ wu,
    const float* __restrict__ sg, const float* __restrict__ su,
    const float* __restrict__ wd, const float* __restrict__ sd,
    const float* __restrict__ x, const float* __restrict__ rmsw,
    const float* __restrict__ router_w,
    uint16_t* __restrict__ wgT, uint16_t* __restrict__ wuT,
    uint16_t* __restrict__ sgT, uint16_t* __restrict__ suT,
    uint16_t* __restrict__ wdT, uint16_t* __restrict__ sdT,
    uint16_t* __restrict__ h, int* __restrict__ topi,
    float* __restrict__ topw, int* __restrict__ counts)
{
  __shared__ uint16_t lds[128 * 256];   // 64 KB: [c_local][r_local] (swizzled)
  int flat0 = blockIdx.x;
  int t = threadIdx.x;
  bool is_tr = (flat0 < 2 * NRG) && ((flat0 & 1) == 0);
  if (is_tr) {
    int flat = flat0 >> 1;              // transpose region 0..NRG-1
    const float* src; uint16_t* dst;
    int Csrc, Rdst, r0, c0;
    if (flat < 1152) {                // D->F: src [2048][1024] -> dst [1024][2048]
      int z = flat >> 6, rem = flat & 63;
      Csrc = FDIM; Rdst = DDIM;
      r0 = (rem >> 3) << 8;           // 8 region-rows of 256
      c0 = (rem & 7) << 7;            // 8 region-cols of 128
      if (z < 8)       { src = wg + (size_t)z * DDIM * FDIM;       dst = wgT + (size_t)z * FDIM * DDIM; }
      else if (z < 16) { src = wu + (size_t)(z - 8) * DDIM * FDIM; dst = wuT + (size_t)(z - 8) * FDIM * DDIM; }
      else if (z == 16){ src = sg; dst = sgT; }
      else             { src = su; dst = suT; }
    } else {                          // F->D: src [1024][2048] -> dst [2048][1024]
      int f2 = flat - 1152;
      int z = f2 >> 6, rem = f2 & 63;
      Csrc = DDIM; Rdst = FDIM;
      r0 = (rem >> 4) << 8;           // 4 region-rows of 256
      c0 = (rem & 15) << 7;           // 16 region-cols of 128
      if (z < 8) { src = wd + (size_t)z * FDIM * DDIM; dst = wdT + (size_t)z * DDIM * FDIM; }
      else       { src = sd; dst = sdT; }
    }
    // phase 1: read 256x128 fp32 (512B runs), convert, LDS-transpose store
    int sub = t >> 5;                 // 0..7: row within iteration group
    int cq = (t & 31) * 4;            // col quad base 0..124
    #pragma unroll 4
    for (int it = 0; it < 32; it++) {
      int r = it * 8 + sub;
      float4 v = *(const float4*)(src + (size_t)(r0 + r) * Csrc + c0 + cq);
      lds[(cq + 0) * 256 + (r ^ SWZ(cq + 0))] = f2bf(v.x);
      lds[(cq + 1) * 256 + (r ^ SWZ(cq + 1))] = f2bf(v.y);
      lds[(cq + 2) * 256 + (r ^ SWZ(cq + 2))] = f2bf(v.z);
      lds[(cq + 3) * 256 + (r ^ SWZ(cq + 3))] = f2bf(v.w);
    }
    __syncthreads();
    // phase 2: write dst rows (c0..c0+127) x 256 cols (512B runs)
    #pragma unroll 4
    for (int it = 0; it < 16; it++) {
      int chunk = it * 256 + t;       // 0..4095
      int cl = chunk >> 5;            // dst row 0..127
      int rch = (chunk & 31) * 8;     // 8-elem col chunk
      uint4 o = *(const uint4*)(lds + cl * 256 + (rch ^ SWZ(cl)));
      *(uint4*)(dst + (size_t)(c0 + cl) * Rdst + r0 + rch) = o;
    }
  } else {
    // ---- RMSNorm + router, wave-per-token ----
    int ridx = (flat0 < 2 * NRG) ? (flat0 >> 1) : (NRG + flat0 - 2 * NRG);
    int wv = t >> 6, lane = t & 63;
    int tok = ridx * 4 + wv;
    const float* xr = x + (size_t)tok * DDIM;

    float4 xv[8], wv8[8];
    #pragma unroll
    for (int j = 0; j < 8; j++) {
      xv[j]  = ((const float4*)xr)[j * 64 + lane];
      wv8[j] = ((const float4*)rmsw)[j * 64 + lane];
    }
    float ss = 0.f;
    #pragma unroll
    for (int j = 0; j < 8; j++)
      ss += xv[j].x * xv[j].x + xv[j].y * xv[j].y + xv[j].z * xv[j].z + xv[j].w * xv[j].w;
    #pragma unroll
    for (int m = 32; m >= 1; m >>= 1) ss += __shfl_xor(ss, m, 64);
    float scale = rsqrtf(ss * (1.0f / DDIM) + 1e-6f);

    float hv[8][4];
    #pragma unroll
    for (int j = 0; j < 8; j++) {
      hv[j][0] = xv[j].x * scale * wv8[j].x;
      hv[j][1] = xv[j].y * scale * wv8[j].y;
      hv[j][2] = xv[j].z * scale * wv8[j].z;
      hv[j][3] = xv[j].w * scale * wv8[j].w;
      ushort4 hw;
      hw.x = f2bf(hv[j][0]); hw.y = f2bf(hv[j][1]);
      hw.z = f2bf(hv[j][2]); hw.w = f2bf(hv[j][3]);
      ((ushort4*)(h + (size_t)tok * DDIM))[j * 64 + lane] = hw;
    }

    float lp[8] = {0, 0, 0, 0, 0, 0, 0, 0};
    #pragma unroll
    for (int j = 0; j < 8; j++) {
      #pragma unroll
      for (int c = 0; c < 4; c++) {
        int d = (j * 64 + lane) * 4 + c;
        const float* rw = router_w + (size_t)d * NEXP;
        float4 a = ((const float4*)rw)[0];
        float4 b = ((const float4*)rw)[1];
        float hj = hv[j][c];
        lp[0] += hj * a.x; lp[1] += hj * a.y; lp[2] += hj * a.z; lp[3] += hj * a.w;
        lp[4] += hj * b.x; lp[5] += hj * b.y; lp[6] += hj * b.z; lp[7] += hj * b.w;
      }
    }
    #pragma unroll
    for (int m = 32; m >= 1; m >>= 1) {
      #pragma unroll
      for (int e = 0; e < 8; e++) lp[e] += __shfl_xor(lp[e], m, 64);
    }
    if (lane == 0) {
      int i0 = 0;
      for (int e = 1; e < 8; e++) if (lp[e] > lp[i0]) i0 = e;   // earliest max
      int i1 = (i0 == 0) ? 1 : 0;
      for (int e = 0; e < 8; e++) if (e != i0 && lp[e] > lp[i1]) i1 = e;
      float p0 = 1.f / (1.f + expf(lp[i1] - lp[i0]));  // renormalized top-2
      topi[tok * 2] = i0; topi[tok * 2 + 1] = i1;
      topw[tok * 2] = p0; topw[tok * 2 + 1] = 1.f - p0;
      atomicAdd(&counts[i0], 1);
      atomicAdd(&counts[i1], 1);
    }
  }
}

// ---------------------------------------------------------------------------
// K3: scatter (offsets computed inline from counts).
// ---------------------------------------------------------------------------
__global__ __launch_bounds__(256) void k_scatter(
    const int* __restrict__ topi, const float* __restrict__ topw,
    const int* __restrict__ counts, int* __restrict__ cursor,
    int* __restrict__ tokslot, float* __restrict__ wtrow)
{
  int offs[10];
  mk_offs(counts, offs);
  int idx = blockIdx.x * 256 + threadIdx.x;   // 0..24575
  if (idx < T_TOK * 2) {
    int t = idx >> 1, k = idx & 1;
    int e = topi[idx];
    int slot = atomicAdd(&cursor[e], 1);
    int row = offs[e] + slot;
    tokslot[row] = t * 4 + k;
    wtrow[row] = topw[idx];
  } else {
    int t = idx - T_TOK * 2;
    int row = offs[8] + t;
    tokslot[row] = t * 4 + 2;
    wtrow[row] = 1.0f;
  }
}

// ---------------------------------------------------------------------------
// GEMM core (proven): 128x128 tile, 4 waves, 64KB dbuf LDS, one
// __syncthreads per K-tile, T2 swizzle, T5 setprio, T1 XCD remap.
// ---------------------------------------------------------------------------
#define BUFA(c) (ldsu + (size_t)(c) * 16384)
#define BUFB(c) (ldsu + 8192 + (size_t)(c) * 16384)

#define XCD_REMAP()                                                            \
  int flat_ = blockIdx.y * GXT + blockIdx.x;                                   \
  int nf_ = (flat_ & 7) * CPX + (flat_ >> 3);                                  \
  int bx = nf_ & (GXT - 1);                                                    \
  int by = nf_ / GXT;

#define STAGE8(T, C) do {                                                     \
  _Pragma("unroll") for (int i_ = 0; i_ < 4; i_++) {                          \
    int G_ = w * 256 + i_ * 64 + lane;                                        \
    gload16(aSrc[i_] + (size_t)(T) * BK, BUFA(C) + G_ * 8);                   \
    gload16(bSrc[i_] + (size_t)(T) * BK, BUFB(C) + G_ * 8);                   \
  } } while (0)

#define COMPUTE_TILE(curA, curB) do {                                         \
  _Pragma("unroll") for (int ks_ = 0; ks_ < 2; ks_++) {                       \
    int ce_ = ks_ * 32 + ((lane >> 4) << 3);                                  \
    bf16x8 av_[4], bv_[4];                                                    \
    _Pragma("unroll") for (int m_ = 0; m_ < 4; m_++) {                        \
      int rr_ = wr * 64 + m_ * 16 + (lane & 15);                              \
      av_[m_] = *(const bf16x8*)((curA) + rr_ * 64 + (ce_ ^ ((rr_ & 7) << 3))); \
    }                                                                         \
    _Pragma("unroll") for (int n_ = 0; n_ < 4; n_++) {                        \
      int rr_ = wc * 64 + n_ * 16 + (lane & 15);                              \
      bv_[n_] = *(const bf16x8*)((curB) + rr_ * 64 + (ce_ ^ ((rr_ & 7) << 3))); \
    }                                                                         \
    __builtin_amdgcn_s_setprio(1);                                            \
    _Pragma("unroll") for (int m_ = 0; m_ < 4; m_++)                          \
    _Pragma("unroll") for (int n_ = 0; n_ < 4; n_++)                          \
      acc[m_][n_] = __builtin_amdgcn_mfma_f32_16x16x32_bf16(av_[m_], bv_[n_], acc[m_][n_], 0, 0, 0); \
    __builtin_amdgcn_s_setprio(0);                                            \
  } } while (0)

// ---------------------------------------------------------------------------
// K5: stage-1 grouped GEMM. Interleaved gate/up B-layout (16-row blocks):
// r -> b=r>>4; type=b&1; fcol = f0 + (b>>1)*16 + (r&15). silu pairing is
// wave-local (acc[m][2p]=gate, acc[m][2p+1]=up).
// ---------------------------------------------------------------------------
__global__ __launch_bounds__(256, 2) void k_stage1(
    const uint16_t* __restrict__ h, const uint16_t* __restrict__ wgT,
    const uint16_t* __restrict__ wuT, const uint16_t* __restrict__ sgT,
    const uint16_t* __restrict__ suT, const int* __restrict__ counts,
    const int* __restrict__ tokslot, uint16_t* __restrict__ A_int)
{
  __shared__ __align__(16) uint16_t ldsu[32768];   // 64 KB

  int offs[10];
  mk_offs(counts, offs);
  XCD_REMAP();
  int row0 = by * 128;
  int end = offs[9];
  if (row0 >= end) return;
  int e = 0;
  #pragma unroll 1
  for (; e < 9; e++) if (row0 >= offs[e] && row0 < offs[e + 1]) break;
  const uint16_t* bg = (e < NEXP) ? wgT + (size_t)e * FDIM * DDIM : sgT;
  const uint16_t* bu = (e < NEXP) ? wuT + (size_t)e * FDIM * DDIM : suT;
  int f0 = bx * 64;

  int tid = threadIdx.x, lane = tid & 63, w = tid >> 6;
  int wr = w & 1, wc = w >> 1;

  const uint16_t* aSrc[4];
  const uint16_t* bSrc[4];
  #pragma unroll
  for (int i = 0; i < 4; i++) {
    int G = w * 256 + i * 64 + lane;
    int r = G >> 3, sl = G & 7;
    int gl = sl ^ (r & 7);
    int ts = tokslot[row0 + r];
    int tok = ts < 0 ? 0 : (ts >> 2);
    aSrc[i] = h + (size_t)tok * DDIM + gl * 8;
    int b = r >> 4;
    int fc = f0 + ((b >> 1) << 4) + (r & 15);
    const uint16_t* wbase = (b & 1) ? bu : bg;
    bSrc[i] = wbase + (size_t)fc * DDIM + gl * 8;
  }

  f32x4 acc[4][4] = {};
  const int NT = DDIM / BK;   // 32

  STAGE8(0, 0);
  __syncthreads();

  #pragma unroll 1
  for (int t = 0; t < NT; ++t) {
    int cur = t & 1;
    if (t + 1 < NT) STAGE8(t + 1, cur ^ 1);
    const uint16_t* curA = BUFA(cur);
    const uint16_t* curB = BUFB(cur);
    COMPUTE_TILE(curA, curB);
    __syncthreads();   // drains vmcnt (t+1 staged) + barrier
  }

  // epilogue: pairs are wave-local (acc[m][2p]=gate, acc[m][2p+1]=up)
  #pragma unroll
  for (int m = 0; m < 4; m++) {
    #pragma unroll
    for (int p = 0; p < 2; p++) {
      #pragma unroll
      for (int r = 0; r < 4; r++) {
        int row = row0 + wr * 64 + m * 16 + ((lane >> 4) << 2) + r;
        int col = f0 + wc * 32 + p * 16 + (lane & 15);
        float g = acc[m][2 * p][r];
        float u = acc[m][2 * p + 1][r];
        float a = (g / (1.f + expf(-g))) * u;
        A_int[(size_t)row * FDIM + col] = f2bf(a);
      }
    }
  }
}

// ---------------------------------------------------------------------------
// K6: stage-2 grouped GEMM: EO = A_int @ W_down. Same core.
// ---------------------------------------------------------------------------
__global__ __launch_bounds__(256, 2) void k_stage2(
    const uint16_t* __restrict__ A_int, const uint16_t* __restrict__ wdT,
    const uint16_t* __restrict__ sdT, const int* __restrict__ counts,
    const int* __restrict__ tokslot, const float* __restrict__ wtrow,
    uint16_t* __restrict__ eo, float* __restrict__ out)
{
  __shared__ __align__(16) uint16_t ldsu[32768];   // 64 KB

  int offs[10];
  mk_offs(counts, offs);
  XCD_REMAP();
  int row0 = by * 128;
  int end = offs[9];
  if (row0 >= end) return;
  int e = 0;
  #pragma unroll 1
  for (; e < 9; e++) if (row0 >= offs[e] && row0 < offs[e + 1]) break;
  const uint16_t* bw = (e < NEXP) ? wdT + (size_t)e * DDIM * FDIM : sdT;
  int d0 = bx * 128;

  int tid = threadIdx.x, lane = tid & 63, w = tid >> 6;
  int wr = w & 1, wc = w >> 1;

  const uint16_t* aSrc[4];
  const uint16_t* bSrc[4];
  #pragma unroll
  for (int i = 0; i < 4; i++) {
    int G = w * 256 + i * 64 + lane;
    int r = G >> 3, sl = G & 7;
    int gl = sl ^ (r & 7);
    aSrc[i] = A_int + (size_t)(row0 + r) * FDIM + gl * 8;
    bSrc[i] = bw + (size_t)(d0 + r) * FDIM + gl * 8;
  }

  f32x4 acc[4][4] = {};
  const int NT = FDIM / BK;   // 16

  STAGE8(0, 0);
  __syncthreads();

  #pragma unroll 1
  for (int t = 0; t < NT; ++t) {
    int cur = t & 1;
    if (t + 1 < NT) STAGE8(t + 1, cur ^ 1);
    const uint16_t* curA = BUFA(cur);
    const uint16_t* curB = BUFB(cur);
    COMPUTE_TILE(curA, curB);
    __syncthreads();
  }

  #pragma unroll
  for (int m = 0; m < 4; m++) {
    #pragma unroll
    for (int r = 0; r < 4; r++) {
      int grow = row0 + wr * 64 + m * 16 + ((lane >> 4) << 2) + r;
      int ts = tokslot[grow];
      if (ts < 0) continue;                  // padded row
      int tok = ts >> 2, slot = ts & 3;
      if (slot == 2) {                       // shared expert -> fp32 out
        size_t obase = (size_t)tok * DDIM;
        #pragma unroll
        for (int n = 0; n < 4; n++) {
          int col = d0 + wc * 64 + n * 16 + (lane & 15);
          out[obase + col] = acc[m][n][r];
        }
      } else {                               // routed -> bf16 weighted slot
        float wt = wtrow[grow];
        size_t obase = ((size_t)tok * 2 + slot) * DDIM;
        #pragma unroll
        for (int n = 0; n < 4; n++) {
          int col = d0 + wc * 64 + n * 16 + (lane & 15);
          eo[obase + col] = f2bf(acc[m][n][r] * wt);
        }
      }
    }
  }
}

// ---------------------------------------------------------------------------
// K7: out = out_shared(fp32) + eo[slot0](bf16) + eo[slot1](bf16)
// ---------------------------------------------------------------------------
__global__ __launch_bounds__(256) void k_final(
    const uint16_t* __restrict__ eo, float* __restrict__ out)
{
  int tok = blockIdx.x;
  int col = threadIdx.x * 8;
  const uint16_t* e0 = eo + ((size_t)tok * 2) * DDIM + col;
  const uint16_t* e1 = eo + ((size_t)tok * 2 + 1) * DDIM + col;
  float* op = out + (size_t)tok * DDIM + col;
  ushort4 a0 = *(const ushort4*)(e0);
  ushort4 a1 = *(const ushort4*)(e0 + 4);
  ushort4 b0 = *(const ushort4*)(e1);
  ushort4 b1 = *(const ushort4*)(e1 + 4);
  float4 s0 = *(const float4*)(op);
  float4 s1 = *(const float4*)(op + 4);
  float4 o0, o1;
  o0.x = s0.x + bf2f(a0.x) + bf2f(b0.x);
  o0.y = s0.y + bf2f(a0.y) + bf2f(b0.y);
  o0.z = s0.z + bf2f(a0.z) + bf2f(b0.z);
  o0.w = s0.w + bf2f(a0.w) + bf2f(b0.w);
  o1.x = s1.x + bf2f(a1.x) + bf2f(b1.x);
  o1.y = s1.y + bf2f(a1.y) + bf2f(b1.y);
  o1.z = s1.z + bf2f(a1.z) + bf2f(b1.z);
  o1.w = s1.w + bf2f(a1.w) + bf2f(b1.w);
  *(float4*)(op) = o0;
  *(float4*)(op + 4) = o1;
}

// ---------------------------------------------------------------------------
extern "C" void kernel_launch(void* const* d_in, const int* in_sizes, int n_in,
                              void* d_out, int out_size, void* d_ws, size_t ws_size,
                              hipStream_t stream) {
  (void)in_sizes; (void)n_in; (void)out_size;
  const float* x    = (const float*)d_in[0];
  const float* rmsw = (const float*)d_in[1];
  const float* rtw  = (const float*)d_in[2];
  const float* wg   = (const float*)d_in[3];
  const float* wu   = (const float*)d_in[4];
  const float* wd   = (const float*)d_in[5];
  const float* sg   = (const float*)d_in[6];
  const float* su   = (const float*)d_in[7];
  const float* sd   = (const float*)d_in[8];
  float* out = (float*)d_out;

  // ---- workspace layout (~200 MB; known-good budget 224.73 MB) ----
  char* base = (char*)d_ws;
  size_t off_b = 0;
  auto place = [&](size_t bytes) { size_t r = off_b; off_b += (bytes + 255) & ~(size_t)255; return r; };
  size_t o_topi    = place((size_t)T_TOK * 2 * 4);
  size_t o_topw    = place((size_t)T_TOK * 2 * 4);
  size_t o_counts  = place(64);
  size_t o_cursor  = place(64);        // adjacent to counts: one 512B memset
  size_t o_tokslot = place((size_t)CAP * 4);
  size_t o_wtrow   = place((size_t)CAP * 4);
  size_t o_h   = place((size_t)T_TOK * DDIM * 2);          // 33.55 MB
  size_t o_wgT = place((size_t)NEXP * FDIM * DDIM * 2);    // 33.55 MB
  size_t o_wuT = place((size_t)NEXP * FDIM * DDIM * 2);    // 33.55 MB
  size_t o_sgT = place((size_t)FDIM * DDIM * 2);           // 4.19 MB
  size_t o_suT = place((size_t)FDIM * DDIM * 2);           // 4.19 MB
  size_t o_wdT = place((size_t)NEXP * DDIM * FDIM * 2);    // 33.55 MB
  size_t o_sdT = place((size_t)DDIM * FDIM * 2);           // 4.19 MB
  size_t o_Ai  = place((size_t)CAP * FDIM * 2);            // 52.43 MB
  // eo (bf16 [T][2][D] = 67.11 MB) overlays h+wgT (both dead after stage1)
  size_t o_eo  = o_h;
  size_t NEED = off_b;
  if (ws_size < NEED) return;

  int*      topi    = (int*)(base + o_topi);
  float*    topw    = (float*)(base + o_topw);
  int*      counts  = (int*)(base + o_counts);
  int*      cursor  = (int*)(base + o_cursor);
  int*      tokslot = (int*)(base + o_tokslot);
  float*    wtrow   = (float*)(base + o_wtrow);
  uint16_t* h       = (uint16_t*)(base + o_h);
  uint16_t* wgT     = (uint16_t*)(base + o_wgT);
  uint16_t* wuT     = (uint16_t*)(base + o_wuT);
  uint16_t* sgT     = (uint16_t*)(base + o_sgT);
  uint16_t* suT     = (uint16_t*)(base + o_suT);
  uint16_t* wdT     = (uint16_t*)(base + o_wdT);
  uint16_t* sdT     = (uint16_t*)(base + o_sdT);
  uint16_t* Ai      = (uint16_t*)(base + o_Ai);
  uint16_t* eo      = (uint16_t*)(base + o_eo);

  hipMemsetAsync(counts, 0, 512, stream);                  // counts + cursor
  hipMemsetAsync(tokslot, 0xFF, (size_t)CAP * 4, stream);  // -1 = padded row

  // interleaved transposes + RMSNorm/router in ONE launch
  k_prep<<<NRG + NRT, 256, 0, stream>>>(
      wg, wu, sg, su, wd, sd, x, rmsw, rtw,
      wgT, wuT, sgT, suT, wdT, sdT, h, topi, topw, counts);

  k_scatter<<<(T_TOK * 3) / 256, 256, 0, stream>>>(topi, topw, counts, cursor, tokslot, wtrow);

  // grids are GXT x NT_M; XCD-chunked remap happens inside the kernels
  k_stage1<<<dim3(GXT, NT_M), 256, 0, stream>>>(h, wgT, wuT, sgT, suT, counts, tokslot, Ai);
  // stage2 overwrites h/wgT (dead) as eo
  k_stage2<<<dim3(GXT, NT_M), 256, 0, stream>>>(Ai, wdT, sdT, counts, tokslot, wtrow, eo, out);
  k_final<<<T_TOK, 256, 0, stream>>>(eo, out);
}

// Round 23
// 675.132 us; speedup vs baseline: 1.0914x; 1.0209x over previous
//
#include <hip/hip_runtime.h>
#include <stdint.h>

// Problem constants (B=4,S=2048 -> T=8192 tokens). Inputs fp32, OUTPUT fp32.
#define T_TOK 8192
#define DDIM  2048
#define NEXP  8
#define FDIM  1024
#define CAP   25600   // 16384 assignments + 8*128 pad + 8192 shared rows
#define NT_M  200     // CAP/128 M-tiles
#define BK    64
#define GXT   16      // grid x (f/d tiles) for both stages
#define NBLK  (GXT * NT_M)   // 3200, divisible by 8
#define CPX   (NBLK / 8)     // 400 blocks per XCD chunk
#define NRG   1728           // transpose regions: 1152 (D->F) + 576 (F->D)
#define NRT   (T_TOK / 4)    // router blocks: 2048
#define NTOT  (NRG + NRT)    // 3776

typedef __bf16 bf16x8 __attribute__((ext_vector_type(8)));
typedef float  f32x4  __attribute__((ext_vector_type(4)));

typedef const __attribute__((address_space(1))) uint32_t* as1_u32;
typedef __attribute__((address_space(3))) uint32_t* as3_u32;

__device__ __forceinline__ void gload16(const void* g, void* l) {
  __builtin_amdgcn_global_load_lds((as1_u32)g, (as3_u32)l, 16, 0, 0);
}
__device__ __forceinline__ float bf2f(uint16_t u) {
  union { uint32_t i; float f; } v; v.i = ((uint32_t)u) << 16; return v.f;
}
__device__ __forceinline__ uint16_t f2bf(float f) {
  union { float f; uint32_t i; } v; v.f = f;
  uint32_t i = v.i;
  i += 0x7FFFu + ((i >> 16) & 1u);   // RNE
  return (uint16_t)(i >> 16);
}
// padded prefix offsets from 8 counts (inline everywhere)
__device__ __forceinline__ void mk_offs(const int* __restrict__ counts, int* o) {
  int a = 0;
  #pragma unroll
  for (int e = 0; e < NEXP; e++) { o[e] = a; a += (counts[e] + 127) & ~127; }
  o[8] = a; o[9] = a + T_TOK;
}

// ---------------------------------------------------------------------------
// K_prep: merged transposes + router, Bresenham-INTERLEAVED block families so
// every CU co-hosts BW-bound transpose waves and latency-bound router waves
// uniformly for the whole dispatch (r22: interleave = -29us).
// Router body stages router_w through LDS (kills 128B-stride gather; body
// numerically proven in r20).
// ---------------------------------------------------------------------------
#define SWZ(c) ((((c) >> 2) & 15) << 3)   // LDS r-swizzle (bits 3-6)

__global__ __launch_bounds__(256) void k_prep(
    const float* __restrict__ wg, const float* __restrict__ wu,
    const float* __restrict__ sg, const float* __restrict__ su,
    const float* __restrict__ wd, const float* __restrict__ sd,
    const float* __restrict__ x, const float* __restrict__ rmsw,
    const float* __restrict__ router_w,
    uint16_t* __restrict__ wgT, uint16_t* __restrict__ wuT,
    uint16_t* __restrict__ sgT, uint16_t* __restrict__ suT,
    uint16_t* __restrict__ wdT, uint16_t* __restrict__ sdT,
    uint16_t* __restrict__ h, int* __restrict__ topi,
    float* __restrict__ topw, int* __restrict__ counts)
{
  __shared__ uint16_t lds[128 * 256];   // 64 KB: tr tile / router rwT
  int flat0 = blockIdx.x;
  int t = threadIdx.x;
  // Bresenham split: exactly NRG transpose blocks spread uniformly over NTOT
  int tr_before = (flat0 * NRG) / NTOT;
  bool is_tr = ((flat0 + 1) * NRG) / NTOT > tr_before;
  if (is_tr) {
    int flat = tr_before;               // transpose region 0..NRG-1
    const float* src; uint16_t* dst;
    int Csrc, Rdst, r0, c0;
    if (flat < 1152) {                // D->F: src [2048][1024] -> dst [1024][2048]
      int z = flat >> 6, rem = flat & 63;
      Csrc = FDIM; Rdst = DDIM;
      r0 = (rem >> 3) << 8;           // 8 region-rows of 256
      c0 = (rem & 7) << 7;            // 8 region-cols of 128
      if (z < 8)       { src = wg + (size_t)z * DDIM * FDIM;       dst = wgT + (size_t)z * FDIM * DDIM; }
      else if (z < 16) { src = wu + (size_t)(z - 8) * DDIM * FDIM; dst = wuT + (size_t)(z - 8) * FDIM * DDIM; }
      else if (z == 16){ src = sg; dst = sgT; }
      else             { src = su; dst = suT; }
    } else {                          // F->D: src [1024][2048] -> dst [2048][1024]
      int f2 = flat - 1152;
      int z = f2 >> 6, rem = f2 & 63;
      Csrc = DDIM; Rdst = FDIM;
      r0 = (rem >> 4) << 8;           // 4 region-rows of 256
      c0 = (rem & 15) << 7;           // 16 region-cols of 128
      if (z < 8) { src = wd + (size_t)z * FDIM * DDIM; dst = wdT + (size_t)z * DDIM * FDIM; }
      else       { src = sd; dst = sdT; }
    }
    // phase 1: read 256x128 fp32 (512B runs), convert, LDS-transpose store
    int sub = t >> 5;                 // 0..7: row within iteration group
    int cq = (t & 31) * 4;            // col quad base 0..124
    #pragma unroll 4
    for (int it = 0; it < 32; it++) {
      int r = it * 8 + sub;
      float4 v = *(const float4*)(src + (size_t)(r0 + r) * Csrc + c0 + cq);
      lds[(cq + 0) * 256 + (r ^ SWZ(cq + 0))] = f2bf(v.x);
      lds[(cq + 1) * 256 + (r ^ SWZ(cq + 1))] = f2bf(v.y);
      lds[(cq + 2) * 256 + (r ^ SWZ(cq + 2))] = f2bf(v.z);
      lds[(cq + 3) * 256 + (r ^ SWZ(cq + 3))] = f2bf(v.w);
    }
    __syncthreads();
    // phase 2: write dst rows (c0..c0+127) x 256 cols (512B runs)
    #pragma unroll 4
    for (int it = 0; it < 16; it++) {
      int chunk = it * 256 + t;       // 0..4095
      int cl = chunk >> 5;            // dst row 0..127
      int rch = (chunk & 31) * 8;     // 8-elem col chunk
      uint4 o = *(const uint4*)(lds + cl * 256 + (rch ^ SWZ(cl)));
      *(uint4*)(dst + (size_t)(c0 + cl) * Rdst + r0 + rch) = o;
    }
  } else {
    // ---- RMSNorm + router, wave-per-token, LDS-staged router_w ----
    int ridx = flat0 - tr_before;       // router block 0..NRT-1
    int wv = t >> 6, lane = t & 63;
    int tok = ridx * 4 + wv;
    const float* xr = x + (size_t)tok * DDIM;

    float4 xv[8], wv8[8];
    #pragma unroll
    for (int j = 0; j < 8; j++) {
      xv[j]  = ((const float4*)xr)[j * 64 + lane];
      wv8[j] = ((const float4*)rmsw)[j * 64 + lane];
    }
    float ss = 0.f;
    #pragma unroll
    for (int j = 0; j < 8; j++)
      ss += xv[j].x * xv[j].x + xv[j].y * xv[j].y + xv[j].z * xv[j].z + xv[j].w * xv[j].w;
    #pragma unroll
    for (int m = 32; m >= 1; m >>= 1) ss += __shfl_xor(ss, m, 64);
    float scale = rsqrtf(ss * (1.0f / DDIM) + 1e-6f);

    float hv[8][4];
    #pragma unroll
    for (int j = 0; j < 8; j++) {
      hv[j][0] = xv[j].x * scale * wv8[j].x;
      hv[j][1] = xv[j].y * scale * wv8[j].y;
      hv[j][2] = xv[j].z * scale * wv8[j].z;
      hv[j][3] = xv[j].w * scale * wv8[j].w;
      ushort4 hw;
      hw.x = f2bf(hv[j][0]); hw.y = f2bf(hv[j][1]);
      hw.z = f2bf(hv[j][2]); hw.w = f2bf(hv[j][3]);
      ((ushort4*)(h + (size_t)tok * DDIM))[j * 64 + lane] = hw;
    }

    // router logits via LDS-staged router_w (r20 body, numerically proven)
    float* rwT = (float*)lds;           // [8][260] floats (~8.1 KB of the 64KB)
    float lp[8] = {0, 0, 0, 0, 0, 0, 0, 0};
    #pragma unroll 1
    for (int j = 0; j < 8; j++) {
      __syncthreads();   // protect previous chunk reads
      {
        // coalesced: thread t loads row j*256+t (32B), scatters to rwT[e][t]
        const float* rrow = router_w + (size_t)(j * 256 + t) * NEXP;
        float4 a = ((const float4*)rrow)[0];
        float4 b = ((const float4*)rrow)[1];
        rwT[0 * 260 + t] = a.x; rwT[1 * 260 + t] = a.y;
        rwT[2 * 260 + t] = a.z; rwT[3 * 260 + t] = a.w;
        rwT[4 * 260 + t] = b.x; rwT[5 * 260 + t] = b.y;
        rwT[6 * 260 + t] = b.z; rwT[7 * 260 + t] = b.w;
      }
      __syncthreads();
      // lane's rows: local (lane*4+c) <-> global (j*64+lane)*4+c
      #pragma unroll
      for (int c = 0; c < 4; c++) {
        float hj = hv[j][c];
        #pragma unroll
        for (int e = 0; e < 8; e++) lp[e] += hj * rwT[e * 260 + lane * 4 + c];
      }
    }
    #pragma unroll
    for (int m = 32; m >= 1; m >>= 1) {
      #pragma unroll
      for (int e = 0; e < 8; e++) lp[e] += __shfl_xor(lp[e], m, 64);
    }
    if (lane == 0) {
      int i0 = 0;
      for (int e = 1; e < 8; e++) if (lp[e] > lp[i0]) i0 = e;   // earliest max
      int i1 = (i0 == 0) ? 1 : 0;
      for (int e = 0; e < 8; e++) if (e != i0 && lp[e] > lp[i1]) i1 = e;
      float p0 = 1.f / (1.f + expf(lp[i1] - lp[i0]));  // renormalized top-2
      topi[tok * 2] = i0; topi[tok * 2 + 1] = i1;
      topw[tok * 2] = p0; topw[tok * 2 + 1] = 1.f - p0;
      atomicAdd(&counts[i0], 1);
      atomicAdd(&counts[i1], 1);
    }
  }
}

// ---------------------------------------------------------------------------
// K3: scatter (offsets computed inline from counts).
// ---------------------------------------------------------------------------
__global__ __launch_bounds__(256) void k_scatter(
    const int* __restrict__ topi, const float* __restrict__ topw,
    const int* __restrict__ counts, int* __restrict__ cursor,
    int* __restrict__ tokslot, float* __restrict__ wtrow)
{
  int offs[10];
  mk_offs(counts, offs);
  int idx = blockIdx.x * 256 + threadIdx.x;   // 0..24575
  if (idx < T_TOK * 2) {
    int t = idx >> 1, k = idx & 1;
    int e = topi[idx];
    int slot = atomicAdd(&cursor[e], 1);
    int row = offs[e] + slot;
    tokslot[row] = t * 4 + k;
    wtrow[row] = topw[idx];
  } else {
    int t = idx - T_TOK * 2;
    int row = offs[8] + t;
    tokslot[row] = t * 4 + 2;
    wtrow[row] = 1.0f;
  }
}

// ---------------------------------------------------------------------------
// GEMM core (proven): 128x128 tile, 4 waves, 64KB dbuf LDS, one
// __syncthreads per K-tile, T2 swizzle, T5 setprio, T1 XCD remap.
// ---------------------------------------------------------------------------
#define BUFA(c) (ldsu + (size_t)(c) * 16384)
#define BUFB(c) (ldsu + 8192 + (size_t)(c) * 16384)

#define XCD_REMAP()                                                            \
  int flat_ = blockIdx.y * GXT + blockIdx.x;                                   \
  int nf_ = (flat_ & 7) * CPX + (flat_ >> 3);                                  \
  int bx = nf_ & (GXT - 1);                                                    \
  int by = nf_ / GXT;

#define STAGE8(T, C) do {                                                     \
  _Pragma("unroll") for (int i_ = 0; i_ < 4; i_++) {                          \
    int G_ = w * 256 + i_ * 64 + lane;                                        \
    gload16(aSrc[i_] + (size_t)(T) * BK, BUFA(C) + G_ * 8);                   \
    gload16(bSrc[i_] + (size_t)(T) * BK, BUFB(C) + G_ * 8);                   \
  } } while (0)

#define COMPUTE_TILE(curA, curB) do {                                         \
  _Pragma("unroll") for (int ks_ = 0; ks_ < 2; ks_++) {                       \
    int ce_ = ks_ * 32 + ((lane >> 4) << 3);                                  \
    bf16x8 av_[4], bv_[4];                                                    \
    _Pragma("unroll") for (int m_ = 0; m_ < 4; m_++) {                        \
      int rr_ = wr * 64 + m_ * 16 + (lane & 15);                              \
      av_[m_] = *(const bf16x8*)((curA) + rr_ * 64 + (ce_ ^ ((rr_ & 7) << 3))); \
    }                                                                         \
    _Pragma("unroll") for (int n_ = 0; n_ < 4; n_++) {                        \
      int rr_ = wc * 64 + n_ * 16 + (lane & 15);                              \
      bv_[n_] = *(const bf16x8*)((curB) + rr_ * 64 + (ce_ ^ ((rr_ & 7) << 3))); \
    }                                                                         \
    __builtin_amdgcn_s_setprio(1);                                            \
    _Pragma("unroll") for (int m_ = 0; m_ < 4; m_++)                          \
    _Pragma("unroll") for (int n_ = 0; n_ < 4; n_++)                          \
      acc[m_][n_] = __builtin_amdgcn_mfma_f32_16x16x32_bf16(av_[m_], bv_[n_], acc[m_][n_], 0, 0, 0); \
    __builtin_amdgcn_s_setprio(0);                                            \
  } } while (0)

// ---------------------------------------------------------------------------
// K5: stage-1 grouped GEMM. Interleaved gate/up B-layout (16-row blocks):
// r -> b=r>>4; type=b&1; fcol = f0 + (b>>1)*16 + (r&15). silu pairing is
// wave-local (acc[m][2p]=gate, acc[m][2p+1]=up).
// ---------------------------------------------------------------------------
__global__ __launch_bounds__(256, 2) void k_stage1(
    const uint16_t* __restrict__ h, const uint16_t* __restrict__ wgT,
    const uint16_t* __restrict__ wuT, const uint16_t* __restrict__ sgT,
    const uint16_t* __restrict__ suT, const int* __restrict__ counts,
    const int* __restrict__ tokslot, uint16_t* __restrict__ A_int)
{
  __shared__ __align__(16) uint16_t ldsu[32768];   // 64 KB

  int offs[10];
  mk_offs(counts, offs);
  XCD_REMAP();
  int row0 = by * 128;
  int end = offs[9];
  if (row0 >= end) return;
  int e = 0;
  #pragma unroll 1
  for (; e < 9; e++) if (row0 >= offs[e] && row0 < offs[e + 1]) break;
  const uint16_t* bg = (e < NEXP) ? wgT + (size_t)e * FDIM * DDIM : sgT;
  const uint16_t* bu = (e < NEXP) ? wuT + (size_t)e * FDIM * DDIM : suT;
  int f0 = bx * 64;

  int tid = threadIdx.x, lane = tid & 63, w = tid >> 6;
  int wr = w & 1, wc = w >> 1;

  const uint16_t* aSrc[4];
  const uint16_t* bSrc[4];
  #pragma unroll
  for (int i = 0; i < 4; i++) {
    int G = w * 256 + i * 64 + lane;
    int r = G >> 3, sl = G & 7;
    int gl = sl ^ (r & 7);
    int ts = tokslot[row0 + r];
    int tok = ts < 0 ? 0 : (ts >> 2);
    aSrc[i] = h + (size_t)tok * DDIM + gl * 8;
    int b = r >> 4;
    int fc = f0 + ((b >> 1) << 4) + (r & 15);
    const uint16_t* wbase = (b & 1) ? bu : bg;
    bSrc[i] = wbase + (size_t)fc * DDIM + gl * 8;
  }

  f32x4 acc[4][4] = {};
  const int NT = DDIM / BK;   // 32

  STAGE8(0, 0);
  __syncthreads();

  #pragma unroll 1
  for (int t = 0; t < NT; ++t) {
    int cur = t & 1;
    if (t + 1 < NT) STAGE8(t + 1, cur ^ 1);
    const uint16_t* curA = BUFA(cur);
    const uint16_t* curB = BUFB(cur);
    COMPUTE_TILE(curA, curB);
    __syncthreads();   // drains vmcnt (t+1 staged) + barrier
  }

  // epilogue: pairs are wave-local (acc[m][2p]=gate, acc[m][2p+1]=up)
  #pragma unroll
  for (int m = 0; m < 4; m++) {
    #pragma unroll
    for (int p = 0; p < 2; p++) {
      #pragma unroll
      for (int r = 0; r < 4; r++) {
        int row = row0 + wr * 64 + m * 16 + ((lane >> 4) << 2) + r;
        int col = f0 + wc * 32 + p * 16 + (lane & 15);
        float g = acc[m][2 * p][r];
        float u = acc[m][2 * p + 1][r];
        float a = (g / (1.f + expf(-g))) * u;
        A_int[(size_t)row * FDIM + col] = f2bf(a);
      }
    }
  }
}

// ---------------------------------------------------------------------------
// K6: stage-2 grouped GEMM: EO = A_int @ W_down. Same core.
// ---------------------------------------------------------------------------
__global__ __launch_bounds__(256, 2) void k_stage2(
    const uint16_t* __restrict__ A_int, const uint16_t* __restrict__ wdT,
    const uint16_t* __restrict__ sdT, const int* __restrict__ counts,
    const int* __restrict__ tokslot, const float* __restrict__ wtrow,
    uint16_t* __restrict__ eo, float* __restrict__ out)
{
  __shared__ __align__(16) uint16_t ldsu[32768];   // 64 KB

  int offs[10];
  mk_offs(counts, offs);
  XCD_REMAP();
  int row0 = by * 128;
  int end = offs[9];
  if (row0 >= end) return;
  int e = 0;
  #pragma unroll 1
  for (; e < 9; e++) if (row0 >= offs[e] && row0 < offs[e + 1]) break;
  const uint16_t* bw = (e < NEXP) ? wdT + (size_t)e * DDIM * FDIM : sdT;
  int d0 = bx * 128;

  int tid = threadIdx.x, lane = tid & 63, w = tid >> 6;
  int wr = w & 1, wc = w >> 1;

  const uint16_t* aSrc[4];
  const uint16_t* bSrc[4];
  #pragma unroll
  for (int i = 0; i < 4; i++) {
    int G = w * 256 + i * 64 + lane;
    int r = G >> 3, sl = G & 7;
    int gl = sl ^ (r & 7);
    aSrc[i] = A_int + (size_t)(row0 + r) * FDIM + gl * 8;
    bSrc[i] = bw + (size_t)(d0 + r) * FDIM + gl * 8;
  }

  f32x4 acc[4][4] = {};
  const int NT = FDIM / BK;   // 16

  STAGE8(0, 0);
  __syncthreads();

  #pragma unroll 1
  for (int t = 0; t < NT; ++t) {
    int cur = t & 1;
    if (t + 1 < NT) STAGE8(t + 1, cur ^ 1);
    const uint16_t* curA = BUFA(cur);
    const uint16_t* curB = BUFB(cur);
    COMPUTE_TILE(curA, curB);
    __syncthreads();
  }

  #pragma unroll
  for (int m = 0; m < 4; m++) {
    #pragma unroll
    for (int r = 0; r < 4; r++) {
      int grow = row0 + wr * 64 + m * 16 + ((lane >> 4) << 2) + r;
      int ts = tokslot[grow];
      if (ts < 0) continue;                  // padded row
      int tok = ts >> 2, slot = ts & 3;
      if (slot == 2) {                       // shared expert -> fp32 out
        size_t obase = (size_t)tok * DDIM;
        #pragma unroll
        for (int n = 0; n < 4; n++) {
          int col = d0 + wc * 64 + n * 16 + (lane & 15);
          out[obase + col] = acc[m][n][r];
        }
      } else {                               // routed -> bf16 weighted slot
        float wt = wtrow[grow];
        size_t obase = ((size_t)tok * 2 + slot) * DDIM;
        #pragma unroll
        for (int n = 0; n < 4; n++) {
          int col = d0 + wc * 64 + n * 16 + (lane & 15);
          eo[obase + col] = f2bf(acc[m][n][r] * wt);
        }
      }
    }
  }
}

// ---------------------------------------------------------------------------
// K7: out = out_shared(fp32) + eo[slot0](bf16) + eo[slot1](bf16)
// ---------------------------------------------------------------------------
__global__ __launch_bounds__(256) void k_final(
    const uint16_t* __restrict__ eo, float* __restrict__ out)
{
  int tok = blockIdx.x;
  int col = threadIdx.x * 8;
  const uint16_t* e0 = eo + ((size_t)tok * 2) * DDIM + col;
  const uint16_t* e1 = eo + ((size_t)tok * 2 + 1) * DDIM + col;
  float* op = out + (size_t)tok * DDIM + col;
  ushort4 a0 = *(const ushort4*)(e0);
  ushort4 a1 = *(const ushort4*)(e0 + 4);
  ushort4 b0 = *(const ushort4*)(e1);
  ushort4 b1 = *(const ushort4*)(e1 + 4);
  float4 s0 = *(const float4*)(op);
  float4 s1 = *(const float4*)(op + 4);
  float4 o0, o1;
  o0.x = s0.x + bf2f(a0.x) + bf2f(b0.x);
  o0.y = s0.y + bf2f(a0.y) + bf2f(b0.y);
  o0.z = s0.z + bf2f(a0.z) + bf2f(b0.z);
  o0.w = s0.w + bf2f(a0.w) + bf2f(b0.w);
  o1.x = s1.x + bf2f(a1.x) + bf2f(b1.x);
  o1.y = s1.y + bf2f(a1.y) + bf2f(b1.y);
  o1.z = s1.z + bf2f(a1.z) + bf2f(b1.z);
  o1.w = s1.w + bf2f(a1.w) + bf2f(b1.w);
  *(float4*)(op) = o0;
  *(float4*)(op + 4) = o1;
}

// ---------------------------------------------------------------------------
extern "C" void kernel_launch(void* const* d_in, const int* in_sizes, int n_in,
                              void* d_out, int out_size, void* d_ws, size_t ws_size,
                              hipStream_t stream) {
  (void)in_sizes; (void)n_in; (void)out_size;
  const float* x    = (const float*)d_in[0];
  const float* rmsw = (const float*)d_in[1];
  const float* rtw  = (const float*)d_in[2];
  const float* wg   = (const float*)d_in[3];
  const float* wu   = (const float*)d_in[4];
  const float* wd   = (const float*)d_in[5];
  const float* sg   = (const float*)d_in[6];
  const float* su   = (const float*)d_in[7];
  const float* sd   = (const float*)d_in[8];
  float* out = (float*)d_out;

  // ---- workspace layout (~200 MB; known-good budget 224.73 MB) ----
  char* base = (char*)d_ws;
  size_t off_b = 0;
  auto place = [&](size_t bytes) { size_t r = off_b; off_b += (bytes + 255) & ~(size_t)255; return r; };
  size_t o_topi    = place((size_t)T_TOK * 2 * 4);
  size_t o_topw    = place((size_t)T_TOK * 2 * 4);
  size_t o_counts  = place(64);
  size_t o_cursor  = place(64);        // adjacent to counts: one 512B memset
  size_t o_tokslot = place((size_t)CAP * 4);
  size_t o_wtrow   = place((size_t)CAP * 4);
  size_t o_h   = place((size_t)T_TOK * DDIM * 2);          // 33.55 MB
  size_t o_wgT = place((size_t)NEXP * FDIM * DDIM * 2);    // 33.55 MB
  size_t o_wuT = place((size_t)NEXP * FDIM * DDIM * 2);    // 33.55 MB
  size_t o_sgT = place((size_t)FDIM * DDIM * 2);           // 4.19 MB
  size_t o_suT = place((size_t)FDIM * DDIM * 2);           // 4.19 MB
  size_t o_wdT = place((size_t)NEXP * DDIM * FDIM * 2);    // 33.55 MB
  size_t o_sdT = place((size_t)DDIM * FDIM * 2);           // 4.19 MB
  size_t o_Ai  = place((size_t)CAP * FDIM * 2);            // 52.43 MB
  // eo (bf16 [T][2][D] = 67.11 MB) overlays h+wgT (both dead after stage1)
  size_t o_eo  = o_h;
  size_t NEED = off_b;
  if (ws_size < NEED) return;

  int*      topi    = (int*)(base + o_topi);
  float*    topw    = (float*)(base + o_topw);
  int*      counts  = (int*)(base + o_counts);
  int*      cursor  = (int*)(base + o_cursor);
  int*      tokslot = (int*)(base + o_tokslot);
  float*    wtrow   = (float*)(base + o_wtrow);
  uint16_t* h       = (uint16_t*)(base + o_h);
  uint16_t* wgT     = (uint16_t*)(base + o_wgT);
  uint16_t* wuT     = (uint16_t*)(base + o_wuT);
  uint16_t* sgT     = (uint16_t*)(base + o_sgT);
  uint16_t* suT     = (uint16_t*)(base + o_suT);
  uint16_t* wdT     = (uint16_t*)(base + o_wdT);
  uint16_t* sdT     = (uint16_t*)(base + o_sdT);
  uint16_t* Ai      = (uint16_t*)(base + o_Ai);
  uint16_t* eo      = (uint16_t*)(base + o_eo);

  hipMemsetAsync(counts, 0, 512, stream);                  // counts + cursor
  hipMemsetAsync(tokslot, 0xFF, (size_t)CAP * 4, stream);  // -1 = padded row

  // Bresenham-interleaved transposes + RMSNorm/router in ONE launch
  k_prep<<<NTOT, 256, 0, stream>>>(
      wg, wu, sg, su, wd, sd, x, rmsw, rtw,
      wgT, wuT, sgT, suT, wdT, sdT, h, topi, topw, counts);

  k_scatter<<<(T_TOK * 3) / 256, 256, 0, stream>>>(topi, topw, counts, cursor, tokslot, wtrow);

  // grids are GXT x NT_M; XCD-chunked remap happens inside the kernels
  k_stage1<<<dim3(GXT, NT_M), 256, 0, stream>>>(h, wgT, wuT, sgT, suT, counts, tokslot, Ai);
  // stage2 overwrites h/wgT (dead) as eo
  k_stage2<<<dim3(GXT, NT_M), 256, 0, stream>>>(Ai, wdT, sdT, counts, tokslot, wtrow, eo, out);
  k_final<<<T_TOK, 256, 0, stream>>>(eo, out);
}

// Round 24
// 669.843 us; speedup vs baseline: 1.1000x; 1.0079x over previous
//
#include <hip/hip_runtime.h>
#include <stdint.h>

// Problem constants (B=4,S=2048 -> T=8192 tokens). Inputs fp32, OUTPUT fp32.
#define T_TOK 8192
#define DDIM  2048
#define NEXP  8
#define FDIM  1024
#define CAP   25600   // 16384 assignments + 8*128 pad + 8192 shared rows
#define NT_M  200     // CAP/128 M-tiles
#define BK    64
#define GXT   16      // grid x (f/d tiles) for both stages
#define NBLK  (GXT * NT_M)   // 3200, divisible by 8
#define CPX   (NBLK / 8)     // 400 blocks per XCD chunk
#define NRG   1728           // transpose regions: 1152 (D->F) + 576 (F->D)
#define NRT   (T_TOK / 4)    // router blocks: 2048
#define NTOT  (NRG + NRT)    // 3776

typedef __bf16 bf16x8 __attribute__((ext_vector_type(8)));
typedef float  f32x4  __attribute__((ext_vector_type(4)));

typedef const __attribute__((address_space(1))) uint32_t* as1_u32;
typedef __attribute__((address_space(3))) uint32_t* as3_u32;

__device__ __forceinline__ void gload16(const void* g, void* l) {
  __builtin_amdgcn_global_load_lds((as1_u32)g, (as3_u32)l, 16, 0, 0);
}
__device__ __forceinline__ float bf2f(uint16_t u) {
  union { uint32_t i; float f; } v; v.i = ((uint32_t)u) << 16; return v.f;
}
__device__ __forceinline__ uint16_t f2bf(float f) {
  union { float f; uint32_t i; } v; v.f = f;
  uint32_t i = v.i;
  i += 0x7FFFu + ((i >> 16) & 1u);   // RNE
  return (uint16_t)(i >> 16);
}
// padded prefix offsets from 8 counts (inline everywhere)
__device__ __forceinline__ void mk_offs(const int* __restrict__ counts, int* o) {
  int a = 0;
  #pragma unroll
  for (int e = 0; e < NEXP; e++) { o[e] = a; a += (counts[e] + 127) & ~127; }
  o[8] = a; o[9] = a + T_TOK;
}

// ---------------------------------------------------------------------------
// K_prep: merged transposes + router, Bresenham-INTERLEAVED block families
// (r22/r23 proven: heterogeneous co-residency = -43us total). Router body
// stages router_w through LDS (kills 128B-stride gather).
// ---------------------------------------------------------------------------
#define SWZ(c) ((((c) >> 2) & 15) << 3)   // LDS r-swizzle (bits 3-6)

__global__ __launch_bounds__(256) void k_prep(
    const float* __restrict__ wg, const float* __restrict__ wu,
    const float* __restrict__ sg, const float* __restrict__ su,
    const float* __restrict__ wd, const float* __restrict__ sd,
    const float* __restrict__ x, const float* __restrict__ rmsw,
    const float* __restrict__ router_w,
    uint16_t* __restrict__ wgT, uint16_t* __restrict__ wuT,
    uint16_t* __restrict__ sgT, uint16_t* __restrict__ suT,
    uint16_t* __restrict__ wdT, uint16_t* __restrict__ sdT,
    uint16_t* __restrict__ h, int* __restrict__ topi,
    float* __restrict__ topw, int* __restrict__ counts)
{
  __shared__ uint16_t lds[128 * 256];   // 64 KB: tr tile / router rwT
  int flat0 = blockIdx.x;
  int t = threadIdx.x;
  // Bresenham split: exactly NRG transpose blocks spread uniformly over NTOT
  int tr_before = (flat0 * NRG) / NTOT;
  bool is_tr = ((flat0 + 1) * NRG) / NTOT > tr_before;
  if (is_tr) {
    int flat = tr_before;               // transpose region 0..NRG-1
    const float* src; uint16_t* dst;
    int Csrc, Rdst, r0, c0;
    if (flat < 1152) {                // D->F: src [2048][1024] -> dst [1024][2048]
      int z = flat >> 6, rem = flat & 63;
      Csrc = FDIM; Rdst = DDIM;
      r0 = (rem >> 3) << 8;           // 8 region-rows of 256
      c0 = (rem & 7) << 7;            // 8 region-cols of 128
      if (z < 8)       { src = wg + (size_t)z * DDIM * FDIM;       dst = wgT + (size_t)z * FDIM * DDIM; }
      else if (z < 16) { src = wu + (size_t)(z - 8) * DDIM * FDIM; dst = wuT + (size_t)(z - 8) * FDIM * DDIM; }
      else if (z == 16){ src = sg; dst = sgT; }
      else             { src = su; dst = suT; }
    } else {                          // F->D: src [1024][2048] -> dst [2048][1024]
      int f2 = flat - 1152;
      int z = f2 >> 6, rem = f2 & 63;
      Csrc = DDIM; Rdst = FDIM;
      r0 = (rem >> 4) << 8;           // 4 region-rows of 256
      c0 = (rem & 15) << 7;           // 16 region-cols of 128
      if (z < 8) { src = wd + (size_t)z * FDIM * DDIM; dst = wdT + (size_t)z * DDIM * FDIM; }
      else       { src = sd; dst = sdT; }
    }
    // phase 1: read 256x128 fp32 (512B runs), convert, LDS-transpose store
    int sub = t >> 5;                 // 0..7: row within iteration group
    int cq = (t & 31) * 4;            // col quad base 0..124
    #pragma unroll 4
    for (int it = 0; it < 32; it++) {
      int r = it * 8 + sub;
      float4 v = *(const float4*)(src + (size_t)(r0 + r) * Csrc + c0 + cq);
      lds[(cq + 0) * 256 + (r ^ SWZ(cq + 0))] = f2bf(v.x);
      lds[(cq + 1) * 256 + (r ^ SWZ(cq + 1))] = f2bf(v.y);
      lds[(cq + 2) * 256 + (r ^ SWZ(cq + 2))] = f2bf(v.z);
      lds[(cq + 3) * 256 + (r ^ SWZ(cq + 3))] = f2bf(v.w);
    }
    __syncthreads();
    // phase 2: write dst rows (c0..c0+127) x 256 cols (512B runs)
    #pragma unroll 4
    for (int it = 0; it < 16; it++) {
      int chunk = it * 256 + t;       // 0..4095
      int cl = chunk >> 5;            // dst row 0..127
      int rch = (chunk & 31) * 8;     // 8-elem col chunk
      uint4 o = *(const uint4*)(lds + cl * 256 + (rch ^ SWZ(cl)));
      *(uint4*)(dst + (size_t)(c0 + cl) * Rdst + r0 + rch) = o;
    }
  } else {
    // ---- RMSNorm + router, wave-per-token, LDS-staged router_w ----
    int ridx = flat0 - tr_before;       // router block 0..NRT-1
    int wv = t >> 6, lane = t & 63;
    int tok = ridx * 4 + wv;
    const float* xr = x + (size_t)tok * DDIM;

    float4 xv[8], wv8[8];
    #pragma unroll
    for (int j = 0; j < 8; j++) {
      xv[j]  = ((const float4*)xr)[j * 64 + lane];
      wv8[j] = ((const float4*)rmsw)[j * 64 + lane];
    }
    float ss = 0.f;
    #pragma unroll
    for (int j = 0; j < 8; j++)
      ss += xv[j].x * xv[j].x + xv[j].y * xv[j].y + xv[j].z * xv[j].z + xv[j].w * xv[j].w;
    #pragma unroll
    for (int m = 32; m >= 1; m >>= 1) ss += __shfl_xor(ss, m, 64);
    float scale = rsqrtf(ss * (1.0f / DDIM) + 1e-6f);

    float hv[8][4];
    #pragma unroll
    for (int j = 0; j < 8; j++) {
      hv[j][0] = xv[j].x * scale * wv8[j].x;
      hv[j][1] = xv[j].y * scale * wv8[j].y;
      hv[j][2] = xv[j].z * scale * wv8[j].z;
      hv[j][3] = xv[j].w * scale * wv8[j].w;
      ushort4 hw;
      hw.x = f2bf(hv[j][0]); hw.y = f2bf(hv[j][1]);
      hw.z = f2bf(hv[j][2]); hw.w = f2bf(hv[j][3]);
      ((ushort4*)(h + (size_t)tok * DDIM))[j * 64 + lane] = hw;
    }

    // router logits via LDS-staged router_w
    float* rwT = (float*)lds;           // [8][260] floats (~8.1 KB of the 64KB)
    float lp[8] = {0, 0, 0, 0, 0, 0, 0, 0};
    #pragma unroll 1
    for (int j = 0; j < 8; j++) {
      __syncthreads();   // protect previous chunk reads
      {
        const float* rrow = router_w + (size_t)(j * 256 + t) * NEXP;
        float4 a = ((const float4*)rrow)[0];
        float4 b = ((const float4*)rrow)[1];
        rwT[0 * 260 + t] = a.x; rwT[1 * 260 + t] = a.y;
        rwT[2 * 260 + t] = a.z; rwT[3 * 260 + t] = a.w;
        rwT[4 * 260 + t] = b.x; rwT[5 * 260 + t] = b.y;
        rwT[6 * 260 + t] = b.z; rwT[7 * 260 + t] = b.w;
      }
      __syncthreads();
      #pragma unroll
      for (int c = 0; c < 4; c++) {
        float hj = hv[j][c];
        #pragma unroll
        for (int e = 0; e < 8; e++) lp[e] += hj * rwT[e * 260 + lane * 4 + c];
      }
    }
    #pragma unroll
    for (int m = 32; m >= 1; m >>= 1) {
      #pragma unroll
      for (int e = 0; e < 8; e++) lp[e] += __shfl_xor(lp[e], m, 64);
    }
    if (lane == 0) {
      int i0 = 0;
      for (int e = 1; e < 8; e++) if (lp[e] > lp[i0]) i0 = e;   // earliest max
      int i1 = (i0 == 0) ? 1 : 0;
      for (int e = 0; e < 8; e++) if (e != i0 && lp[e] > lp[i1]) i1 = e;
      float p0 = 1.f / (1.f + expf(lp[i1] - lp[i0]));  // renormalized top-2
      topi[tok * 2] = i0; topi[tok * 2 + 1] = i1;
      topw[tok * 2] = p0; topw[tok * 2 + 1] = 1.f - p0;
      atomicAdd(&counts[i0], 1);
      atomicAdd(&counts[i1], 1);
    }
  }
}

// ---------------------------------------------------------------------------
// K3: scatter (offsets computed inline from counts).
// ---------------------------------------------------------------------------
__global__ __launch_bounds__(256) void k_scatter(
    const int* __restrict__ topi, const float* __restrict__ topw,
    const int* __restrict__ counts, int* __restrict__ cursor,
    int* __restrict__ tokslot, float* __restrict__ wtrow)
{
  int offs[10];
  mk_offs(counts, offs);
  int idx = blockIdx.x * 256 + threadIdx.x;   // 0..24575
  if (idx < T_TOK * 2) {
    int t = idx >> 1, k = idx & 1;
    int e = topi[idx];
    int slot = atomicAdd(&cursor[e], 1);
    int row = offs[e] + slot;
    tokslot[row] = t * 4 + k;
    wtrow[row] = topw[idx];
  } else {
    int t = idx - T_TOK * 2;
    int row = offs[8] + t;
    tokslot[row] = t * 4 + 2;
    wtrow[row] = 1.0f;
  }
}

// ---------------------------------------------------------------------------
// GEMM core (proven): 128x128 tile, 4 waves, 64KB dbuf LDS, one
// __syncthreads per K-tile, T2 swizzle, T5 setprio, T1 XCD remap.
// ---------------------------------------------------------------------------
#define BUFA(c) (ldsu + (size_t)(c) * 16384)
#define BUFB(c) (ldsu + 8192 + (size_t)(c) * 16384)

#define XCD_REMAP()                                                            \
  int flat_ = blockIdx.y * GXT + blockIdx.x;                                   \
  int nf_ = (flat_ & 7) * CPX + (flat_ >> 3);                                  \
  int bx = nf_ & (GXT - 1);                                                    \
  int by = nf_ / GXT;

#define STAGE8(T, C) do {                                                     \
  _Pragma("unroll") for (int i_ = 0; i_ < 4; i_++) {                          \
    int G_ = w * 256 + i_ * 64 + lane;                                        \
    gload16(aSrc[i_] + (size_t)(T) * BK, BUFA(C) + G_ * 8);                   \
    gload16(bSrc[i_] + (size_t)(T) * BK, BUFB(C) + G_ * 8);                   \
  } } while (0)

#define COMPUTE_TILE(curA, curB) do {                                         \
  _Pragma("unroll") for (int ks_ = 0; ks_ < 2; ks_++) {                       \
    int ce_ = ks_ * 32 + ((lane >> 4) << 3);                                  \
    bf16x8 av_[4], bv_[4];                                                    \
    _Pragma("unroll") for (int m_ = 0; m_ < 4; m_++) {                        \
      int rr_ = wr * 64 + m_ * 16 + (lane & 15);                              \
      av_[m_] = *(const bf16x8*)((curA) + rr_ * 64 + (ce_ ^ ((rr_ & 7) << 3))); \
    }                                                                         \
    _Pragma("unroll") for (int n_ = 0; n_ < 4; n_++) {                        \
      int rr_ = wc * 64 + n_ * 16 + (lane & 15);                              \
      bv_[n_] = *(const bf16x8*)((curB) + rr_ * 64 + (ce_ ^ ((rr_ & 7) << 3))); \
    }                                                                         \
    __builtin_amdgcn_s_setprio(1);                                            \
    _Pragma("unroll") for (int m_ = 0; m_ < 4; m_++)                          \
    _Pragma("unroll") for (int n_ = 0; n_ < 4; n_++)                          \
      acc[m_][n_] = __builtin_amdgcn_mfma_f32_16x16x32_bf16(av_[m_], bv_[n_], acc[m_][n_], 0, 0, 0); \
    __builtin_amdgcn_s_setprio(0);                                            \
  } } while (0)

// ---------------------------------------------------------------------------
// K5: stage-1 grouped GEMM. Interleaved gate/up B-layout (16-row blocks):
// r -> b=r>>4; type=b&1; fcol = f0 + (b>>1)*16 + (r&15). silu pairing is
// wave-local (acc[m][2p]=gate, acc[m][2p+1]=up).
// ---------------------------------------------------------------------------
__global__ __launch_bounds__(256, 2) void k_stage1(
    const uint16_t* __restrict__ h, const uint16_t* __restrict__ wgT,
    const uint16_t* __restrict__ wuT, const uint16_t* __restrict__ sgT,
    const uint16_t* __restrict__ suT, const int* __restrict__ counts,
    const int* __restrict__ tokslot, uint16_t* __restrict__ A_int)
{
  __shared__ __align__(16) uint16_t ldsu[32768];   // 64 KB

  int offs[10];
  mk_offs(counts, offs);
  XCD_REMAP();
  int row0 = by * 128;
  int end = offs[9];
  if (row0 >= end) return;
  int e = 0;
  #pragma unroll 1
  for (; e < 9; e++) if (row0 >= offs[e] && row0 < offs[e + 1]) break;
  const uint16_t* bg = (e < NEXP) ? wgT + (size_t)e * FDIM * DDIM : sgT;
  const uint16_t* bu = (e < NEXP) ? wuT + (size_t)e * FDIM * DDIM : suT;
  int f0 = bx * 64;

  int tid = threadIdx.x, lane = tid & 63, w = tid >> 6;
  int wr = w & 1, wc = w >> 1;

  const uint16_t* aSrc[4];
  const uint16_t* bSrc[4];
  #pragma unroll
  for (int i = 0; i < 4; i++) {
    int G = w * 256 + i * 64 + lane;
    int r = G >> 3, sl = G & 7;
    int gl = sl ^ (r & 7);
    int ts = tokslot[row0 + r];
    int tok = ts < 0 ? 0 : (ts >> 2);
    aSrc[i] = h + (size_t)tok * DDIM + gl * 8;
    int b = r >> 4;
    int fc = f0 + ((b >> 1) << 4) + (r & 15);
    const uint16_t* wbase = (b & 1) ? bu : bg;
    bSrc[i] = wbase + (size_t)fc * DDIM + gl * 8;
  }

  f32x4 acc[4][4] = {};
  const int NT = DDIM / BK;   // 32

  STAGE8(0, 0);
  __syncthreads();

  #pragma unroll 1
  for (int t = 0; t < NT; ++t) {
    int cur = t & 1;
    if (t + 1 < NT) STAGE8(t + 1, cur ^ 1);
    const uint16_t* curA = BUFA(cur);
    const uint16_t* curB = BUFB(cur);
    COMPUTE_TILE(curA, curB);
    __syncthreads();   // drains vmcnt (t+1 staged) + barrier
  }

  // epilogue: pairs are wave-local (acc[m][2p]=gate, acc[m][2p+1]=up)
  #pragma unroll
  for (int m = 0; m < 4; m++) {
    #pragma unroll
    for (int p = 0; p < 2; p++) {
      #pragma unroll
      for (int r = 0; r < 4; r++) {
        int row = row0 + wr * 64 + m * 16 + ((lane >> 4) << 2) + r;
        int col = f0 + wc * 32 + p * 16 + (lane & 15);
        float g = acc[m][2 * p][r];
        float u = acc[m][2 * p + 1][r];
        float a = (g / (1.f + expf(-g))) * u;
        A_int[(size_t)row * FDIM + col] = f2bf(a);
      }
    }
  }
}

// ---------------------------------------------------------------------------
// K6: stage-2 grouped GEMM: EO = A_int @ W_down. Same core.
// ALL rows (routed slot 0/1 AND shared slot 2) write bf16*wt into
// eo[tok*3+slot] — branch-free epilogue (wtrow=1.0 for shared).
// ---------------------------------------------------------------------------
__global__ __launch_bounds__(256, 2) void k_stage2(
    const uint16_t* __restrict__ A_int, const uint16_t* __restrict__ wdT,
    const uint16_t* __restrict__ sdT, const int* __restrict__ counts,
    const int* __restrict__ tokslot, const float* __restrict__ wtrow,
    uint16_t* __restrict__ eo)
{
  __shared__ __align__(16) uint16_t ldsu[32768];   // 64 KB

  int offs[10];
  mk_offs(counts, offs);
  XCD_REMAP();
  int row0 = by * 128;
  int end = offs[9];
  if (row0 >= end) return;
  int e = 0;
  #pragma unroll 1
  for (; e < 9; e++) if (row0 >= offs[e] && row0 < offs[e + 1]) break;
  const uint16_t* bw = (e < NEXP) ? wdT + (size_t)e * DDIM * FDIM : sdT;
  int d0 = bx * 128;

  int tid = threadIdx.x, lane = tid & 63, w = tid >> 6;
  int wr = w & 1, wc = w >> 1;

  const uint16_t* aSrc[4];
  const uint16_t* bSrc[4];
  #pragma unroll
  for (int i = 0; i < 4; i++) {
    int G = w * 256 + i * 64 + lane;
    int r = G >> 3, sl = G & 7;
    int gl = sl ^ (r & 7);
    aSrc[i] = A_int + (size_t)(row0 + r) * FDIM + gl * 8;
    bSrc[i] = bw + (size_t)(d0 + r) * FDIM + gl * 8;
  }

  f32x4 acc[4][4] = {};
  const int NT = FDIM / BK;   // 16

  STAGE8(0, 0);
  __syncthreads();

  #pragma unroll 1
  for (int t = 0; t < NT; ++t) {
    int cur = t & 1;
    if (t + 1 < NT) STAGE8(t + 1, cur ^ 1);
    const uint16_t* curA = BUFA(cur);
    const uint16_t* curB = BUFB(cur);
    COMPUTE_TILE(curA, curB);
    __syncthreads();
  }

  #pragma unroll
  for (int m = 0; m < 4; m++) {
    #pragma unroll
    for (int r = 0; r < 4; r++) {
      int grow = row0 + wr * 64 + m * 16 + ((lane >> 4) << 2) + r;
      int ts = tokslot[grow];
      if (ts < 0) continue;                  // padded row
      int tok = ts >> 2, slot = ts & 3;
      float wt = wtrow[grow];                // 1.0 for shared rows
      size_t obase = ((size_t)tok * 3 + slot) * DDIM;
      #pragma unroll
      for (int n = 0; n < 4; n++) {
        int col = d0 + wc * 64 + n * 16 + (lane & 15);
        eo[obase + col] = f2bf(acc[m][n][r] * wt);
      }
    }
  }
}

// ---------------------------------------------------------------------------
// K7: out = eo[slot0] + eo[slot1] + eo[slot2]   (bf16 reads, fp32 write;
// no read of out -> 68MB less traffic than the old read-modify-write)
// ---------------------------------------------------------------------------
__global__ __launch_bounds__(256) void k_final(
    const uint16_t* __restrict__ eo, float* __restrict__ out)
{
  int tok = blockIdx.x;
  int col = threadIdx.x * 8;
  const uint16_t* e0 = eo + ((size_t)tok * 3) * DDIM + col;
  const uint16_t* e1 = e0 + DDIM;
  const uint16_t* e2 = e1 + DDIM;
  float* op = out + (size_t)tok * DDIM + col;
  ushort4 a0 = *(const ushort4*)(e0);
  ushort4 a1 = *(const ushort4*)(e0 + 4);
  ushort4 b0 = *(const ushort4*)(e1);
  ushort4 b1 = *(const ushort4*)(e1 + 4);
  ushort4 c0 = *(const ushort4*)(e2);
  ushort4 c1 = *(const ushort4*)(e2 + 4);
  float4 o0, o1;
  o0.x = bf2f(a0.x) + bf2f(b0.x) + bf2f(c0.x);
  o0.y = bf2f(a0.y) + bf2f(b0.y) + bf2f(c0.y);
  o0.z = bf2f(a0.z) + bf2f(b0.z) + bf2f(c0.z);
  o0.w = bf2f(a0.w) + bf2f(b0.w) + bf2f(c0.w);
  o1.x = bf2f(a1.x) + bf2f(b1.x) + bf2f(c1.x);
  o1.y = bf2f(a1.y) + bf2f(b1.y) + bf2f(c1.y);
  o1.z = bf2f(a1.z) + bf2f(b1.z) + bf2f(c1.z);
  o1.w = bf2f(a1.w) + bf2f(b1.w) + bf2f(c1.w);
  *(float4*)(op) = o0;
  *(float4*)(op + 4) = o1;
}

// ---------------------------------------------------------------------------
extern "C" void kernel_launch(void* const* d_in, const int* in_sizes, int n_in,
                              void* d_out, int out_size, void* d_ws, size_t ws_size,
                              hipStream_t stream) {
  (void)in_sizes; (void)n_in; (void)out_size;
  const float* x    = (const float*)d_in[0];
  const float* rmsw = (const float*)d_in[1];
  const float* rtw  = (const float*)d_in[2];
  const float* wg   = (const float*)d_in[3];
  const float* wu   = (const float*)d_in[4];
  const float* wd   = (const float*)d_in[5];
  const float* sg   = (const float*)d_in[6];
  const float* su   = (const float*)d_in[7];
  const float* sd   = (const float*)d_in[8];
  float* out = (float*)d_out;

  // ---- workspace layout (~200 MB; known-good budget 224.73 MB) ----
  char* base = (char*)d_ws;
  size_t off_b = 0;
  auto place = [&](size_t bytes) { size_t r = off_b; off_b += (bytes + 255) & ~(size_t)255; return r; };
  size_t o_topi    = place((size_t)T_TOK * 2 * 4);
  size_t o_topw    = place((size_t)T_TOK * 2 * 4);
  size_t o_counts  = place(64);
  size_t o_cursor  = place(64);        // adjacent to counts: one 512B memset
  size_t o_tokslot = place((size_t)CAP * 4);
  size_t o_wtrow   = place((size_t)CAP * 4);
  size_t o_h   = place((size_t)T_TOK * DDIM * 2);          // 33.55 MB
  size_t o_wgT = place((size_t)NEXP * FDIM * DDIM * 2);    // 33.55 MB
  size_t o_wuT = place((size_t)NEXP * FDIM * DDIM * 2);    // 33.55 MB
  size_t o_sgT = place((size_t)FDIM * DDIM * 2);           // 4.19 MB
  size_t o_suT = place((size_t)FDIM * DDIM * 2);           // 4.19 MB
  size_t o_wdT = place((size_t)NEXP * DDIM * FDIM * 2);    // 33.55 MB
  size_t o_sdT = place((size_t)DDIM * FDIM * 2);           // 4.19 MB
  size_t o_Ai  = place((size_t)CAP * FDIM * 2);            // 52.43 MB
  // eo (bf16 [T][3][D] = 100.66 MB) overlays h+wgT+wuT exactly (all dead
  // after stage1: 3 x 33,554,432 B = 100,663,296 B)
  size_t o_eo  = o_h;
  size_t NEED = off_b;
  if (ws_size < NEED) return;

  int*      topi    = (int*)(base + o_topi);
  float*    topw    = (float*)(base + o_topw);
  int*      counts  = (int*)(base + o_counts);
  int*      cursor  = (int*)(base + o_cursor);
  int*      tokslot = (int*)(base + o_tokslot);
  float*    wtrow   = (float*)(base + o_wtrow);
  uint16_t* h       = (uint16_t*)(base + o_h);
  uint16_t* wgT     = (uint16_t*)(base + o_wgT);
  uint16_t* wuT     = (uint16_t*)(base + o_wuT);
  uint16_t* sgT     = (uint16_t*)(base + o_sgT);
  uint16_t* suT     = (uint16_t*)(base + o_suT);
  uint16_t* wdT     = (uint16_t*)(base + o_wdT);
  uint16_t* sdT     = (uint16_t*)(base + o_sdT);
  uint16_t* Ai      = (uint16_t*)(base + o_Ai);
  uint16_t* eo      = (uint16_t*)(base + o_eo);

  hipMemsetAsync(counts, 0, 512, stream);                  // counts + cursor
  hipMemsetAsync(tokslot, 0xFF, (size_t)CAP * 4, stream);  // -1 = padded row

  // Bresenham-interleaved transposes + RMSNorm/router in ONE launch
  k_prep<<<NTOT, 256, 0, stream>>>(
      wg, wu, sg, su, wd, sd, x, rmsw, rtw,
      wgT, wuT, sgT, suT, wdT, sdT, h, topi, topw, counts);

  k_scatter<<<(T_TOK * 3) / 256, 256, 0, stream>>>(topi, topw, counts, cursor, tokslot, wtrow);

  // grids are GXT x NT_M; XCD-chunked remap happens inside the kernels
  k_stage1<<<dim3(GXT, NT_M), 256, 0, stream>>>(h, wgT, wuT, sgT, suT, counts, tokslot, Ai);
  // stage2 overwrites h/wgT/wuT (dead) as eo[T][3][D]
  k_stage2<<<dim3(GXT, NT_M), 256, 0, stream>>>(Ai, wdT, sdT, counts, tokslot, wtrow, eo);
  k_final<<<T_TOK, 256, 0, stream>>>(eo, out);
}